// Round 1
// baseline (10017.479 us; speedup 1.0000x reference)
//
#include <hip/hip_runtime.h>
#include <cmath>

#define NM 1043
#define ND 2166

static inline int ceil_div(int a, int b) { return (a + b - 1) / b; }

// ---------------- generic tiled f32 GEMM ----------------
// C[M,N] = A @ B ; A is M x K row-major (TRANS_A=0) or K x M row-major read as
// A[k*lda + m] (TRANS_A=1). B is K x N row-major.
template<int TRANS_A>
__global__ __launch_bounds__(256) void gemm_f32(
    const float* __restrict__ A, const float* __restrict__ B, float* __restrict__ C,
    int M, int N, int K, int lda, int ldb, int ldc) {
  __shared__ float As[16][65];
  __shared__ float Bs[16][65];
  const int tid = threadIdx.x;
  const int tx = tid & 15, ty = tid >> 4;
  const int bm = blockIdx.y << 6, bn = blockIdx.x << 6;
  float acc[4][4] = {};
  for (int k0 = 0; k0 < K; k0 += 16) {
    if (TRANS_A) {
      for (int i = tid; i < 16 * 64; i += 256) {
        int kk = i >> 6, mm = i & 63;
        int r = k0 + kk, c = bm + mm;
        As[kk][mm] = (r < K && c < M) ? A[(size_t)r * lda + c] : 0.f;
      }
    } else {
      for (int i = tid; i < 16 * 64; i += 256) {
        int kk = i & 15, mm = i >> 4;
        int r = bm + mm, c = k0 + kk;
        As[kk][mm] = (r < M && c < K) ? A[(size_t)r * lda + c] : 0.f;
      }
    }
    for (int i = tid; i < 16 * 64; i += 256) {
      int kk = i >> 6, nn = i & 63;
      int r = k0 + kk, c = bn + nn;
      Bs[kk][nn] = (r < K && c < N) ? B[(size_t)r * ldb + c] : 0.f;
    }
    __syncthreads();
#pragma unroll
    for (int kk = 0; kk < 16; kk++) {
      float a[4], b[4];
#pragma unroll
      for (int i = 0; i < 4; i++) a[i] = As[kk][ty + (i << 4)];
#pragma unroll
      for (int j = 0; j < 4; j++) b[j] = Bs[kk][tx + (j << 4)];
#pragma unroll
      for (int i = 0; i < 4; i++)
#pragma unroll
        for (int j = 0; j < 4; j++) acc[i][j] += a[i] * b[j];
    }
    __syncthreads();
  }
#pragma unroll
  for (int i = 0; i < 4; i++) {
    int r = bm + ty + (i << 4);
    if (r >= M) continue;
#pragma unroll
    for (int j = 0; j < 4; j++) {
      int c = bn + tx + (j << 4);
      if (c < N) C[(size_t)r * ldc + c] = acc[i][j];
    }
  }
}

// ---------------- GCN pieces ----------------
__global__ __launch_bounds__(256) void deg_scatter(const int* __restrict__ dst,
                                                   const float* __restrict__ w,
                                                   float* __restrict__ deg, int m) {
  int e = blockIdx.x * 256 + threadIdx.x;
  if (e < m) atomicAdd(&deg[dst[e]], w[e]);
}

__global__ __launch_bounds__(256) void finish_dis(float* __restrict__ deg, int n) {
  int i = blockIdx.x * 256 + threadIdx.x;
  if (i < n) deg[i] = rsqrtf(deg[i] + 1.0f);  // +1 = self-loop weight
}

// agg[dst] += dis[src]*w*dis[dst] * h[src]; 128 threads/edge, 4 floats/thread
__global__ __launch_bounds__(256) void gcn_scatter(const int* __restrict__ src,
                                                   const int* __restrict__ dst,
                                                   const float* __restrict__ w,
                                                   const float* __restrict__ dis,
                                                   const float* __restrict__ h,
                                                   float* __restrict__ agg, int m) {
  int t = blockIdx.x * 256 + threadIdx.x;
  int e = t >> 7;
  if (e >= m) return;
  int f = (t & 127) << 2;
  int s = src[e], d = dst[e];
  float nrm = dis[s] * w[e] * dis[d];
  const float4 hv = *reinterpret_cast<const float4*>(h + ((size_t)s << 9) + f);
  float* ap = agg + ((size_t)d << 9) + f;
  atomicAdd(ap + 0, nrm * hv.x);
  atomicAdd(ap + 1, nrm * hv.y);
  atomicAdd(ap + 2, nrm * hv.z);
  atomicAdd(ap + 3, nrm * hv.w);
}

// out[node, f] = relu(agg + dis^2*h + b), out has row stride ldo (writes into emb)
__global__ __launch_bounds__(256) void gcn_epilogue(const float* __restrict__ agg,
                                                    const float* __restrict__ h,
                                                    const float* __restrict__ dis,
                                                    const float* __restrict__ b,
                                                    float* __restrict__ out, int n, int ldo) {
  int i = blockIdx.x * 256 + threadIdx.x;
  if (i >= n * 512) return;
  int node = i >> 9, f = i & 511;
  float di = dis[node];
  float v = agg[i] + di * di * h[i] + b[f];
  out[(size_t)node * ldo + f] = fmaxf(v, 0.f);
}

// ---------------- view gather: xv[(v*n+nn)*512+e] = emb_flat[(v*512+e)*n+nn] ----
__global__ __launch_bounds__(256) void gather_view(const float* __restrict__ emb,
                                                   float* __restrict__ xv, int n) {
  size_t i = (size_t)blockIdx.x * 256 + threadIdx.x;
  size_t total = (size_t)n * 2048;
  if (i >= total) return;
  int e = (int)(i & 511);
  size_t t = i >> 9;  // v*n + nn
  int v = (int)(t / n);
  int nn = (int)(t - (size_t)v * n);
  xv[i] = emb[((size_t)v * 512 + e) * n + nn];
}

// ---------------- flash attention, hd=64, 8 heads, 4 views ----------------
// Q,K,V,O layout: [(v*N + n)*512 + h*64 + d]. 4 waves/block, 8 rows/wave.
#define ATT_RW 8
#define ATT_R 32
__global__ __launch_bounds__(256) void attn_kernel(const float* __restrict__ Q,
                                                   const float* __restrict__ K,
                                                   const float* __restrict__ V,
                                                   float* __restrict__ O, int N) {
  __shared__ float kt[64][65];
  __shared__ float vt[64][65];
  __shared__ float qs[ATT_R][64];
  __shared__ float ps[ATT_R][64];
  const int tid = threadIdx.x;
  const int lane = tid & 63, w = tid >> 6;
  const int vh = blockIdx.y;  // 0..31
  const int v = vh >> 3, h = vh & 7;
  const int rowbase = blockIdx.x * ATT_R;
  const float* Qb = Q + (size_t)v * N * 512 + h * 64;
  const float* Kb = K + (size_t)v * N * 512 + h * 64;
  const float* Vb = V + (size_t)v * N * 512 + h * 64;

  for (int i = tid; i < ATT_R * 64; i += 256) {
    int r = i >> 6, d = i & 63;
    int row = rowbase + r;
    qs[r][d] = (row < N) ? Qb[(size_t)row * 512 + d] * 0.125f : 0.f;  // 1/sqrt(64)
  }
  __syncthreads();

  float run_max[ATT_RW], run_sum[ATT_RW], oacc[ATT_RW];
#pragma unroll
  for (int r = 0; r < ATT_RW; r++) { run_max[r] = -INFINITY; run_sum[r] = 0.f; oacc[r] = 0.f; }

  const int ntiles = (N + 63) >> 6;
  for (int mt = 0; mt < ntiles; mt++) {
    const int mbase = mt << 6;
    for (int i = tid; i < 64 * 64; i += 256) {
      int r = i >> 6, d = i & 63;
      int m = mbase + r;
      float kv = 0.f, vv = 0.f;
      if (m < N) {
        kv = Kb[(size_t)m * 512 + d];
        vv = Vb[(size_t)m * 512 + d];
      }
      kt[r][d] = kv;
      vt[r][d] = vv;
    }
    __syncthreads();

    const bool mvalid = (mbase + lane) < N;
#pragma unroll
    for (int r = 0; r < ATT_RW; r++) {
      const int qr = w * ATT_RW + r;
      float s = 0.f;
#pragma unroll 16
      for (int d = 0; d < 64; d++) s += qs[qr][d] * kt[lane][d];
      if (!mvalid) s = -INFINITY;
      float tmax = s;
      for (int off = 32; off; off >>= 1) tmax = fmaxf(tmax, __shfl_xor(tmax, off));
      float nm = fmaxf(run_max[r], tmax);
      float scale = __expf(run_max[r] - nm);
      float pv = __expf(s - nm);
      float tsum = pv;
      for (int off = 32; off; off >>= 1) tsum += __shfl_xor(tsum, off);
      run_sum[r] = run_sum[r] * scale + tsum;
      run_max[r] = nm;
      oacc[r] *= scale;
      ps[qr][lane] = pv;  // wave-internal LDS, in-order, no barrier needed
    }
    for (int l = 0; l < 64; l++) {
      float vv = vt[l][lane];
#pragma unroll
      for (int r = 0; r < ATT_RW; r++) oacc[r] += ps[w * ATT_RW + r][l] * vv;
    }
    __syncthreads();
  }

  float* Ob = O + (size_t)v * N * 512 + h * 64;
#pragma unroll
  for (int r = 0; r < ATT_RW; r++) {
    int row = rowbase + w * ATT_RW + r;
    if (row < N) Ob[(size_t)row * 512 + lane] = oacc[r] / run_sum[r];
  }
}

// ---------------- fuse: y[n*512+e] = fb + sum_c fw[c]*mha[(c*N+n)*512+e] -------
__global__ __launch_bounds__(256) void fuse_kernel(const float* __restrict__ mha,
                                                   const float* __restrict__ fw,
                                                   const float* __restrict__ fb,
                                                   float* __restrict__ y, int n) {
  int i = blockIdx.x * 256 + threadIdx.x;
  if (i >= n * 512) return;
  size_t stride = (size_t)n * 512;
  float acc = fb[0];
  acc += fw[0] * mha[i];
  acc += fw[1] * mha[stride + i];
  acc += fw[2] * mha[2 * stride + i];
  acc += fw[3] * mha[3 * stride + i];
  y[i] = acc;
}

// ---------------- launch ----------------
extern "C" void kernel_launch(void* const* d_in, const int* in_sizes, int n_in,
                              void* d_out, int out_size, void* d_ws, size_t ws_size,
                              hipStream_t stream) {
  const float* mirna_x = (const float*)d_in[0];
  const float* drug_x  = (const float*)d_in[1];
  const int*   e_mm1 = (const int*)d_in[2];  const float* a_mm1 = (const float*)d_in[3];
  const int*   e_mm2 = (const int*)d_in[4];  const float* a_mm2 = (const float*)d_in[5];
  const int*   e_dd1 = (const int*)d_in[6];  const float* a_dd1 = (const float*)d_in[7];
  const int*   e_dd2 = (const int*)d_in[8];  const float* a_dd2 = (const float*)d_in[9];
  const int m_mm1 = in_sizes[2] / 2, m_mm2 = in_sizes[4] / 2;
  const int m_dd1 = in_sizes[6] / 2, m_dd2 = in_sizes[8] / 2;
  float* out = (float*)d_out;

  // workspace carve (f32 elems, 256-elem aligned)
  float* ws = (float*)d_ws;
  size_t off = 0;
  auto take = [&](size_t nelem) {
    float* r = ws + off;
    off += (nelem + 255) & ~(size_t)255;
    return r;
  };
  float* emb_m = take((size_t)NM * 2048);
  float* emb_d = take((size_t)ND * 2048);
  float* hbuf  = take((size_t)ND * 512);
  float* agg   = take((size_t)ND * 512);
  float* dis   = take(4096);
  float* xv_m  = take((size_t)NM * 2048);  // later reused as o2_m
  float* Qm    = take((size_t)NM * 2048);  // later reused as mha_m
  float* Km    = take((size_t)NM * 2048);
  float* Vm    = take((size_t)NM * 2048);
  float* xv_d  = take((size_t)ND * 2048);  // later reused as o2_d
  float* Qd    = take((size_t)ND * 2048);  // later reused as mha_d
  float* Kd    = take((size_t)ND * 2048);
  float* Vd    = take((size_t)ND * 2048);
  float* y_m   = take((size_t)NM * 512);
  float* y_d   = take((size_t)ND * 512);

  auto enc = [&](const float* x, int n, const int* edge, const float* attr, int m,
                 const float* W1, const float* b1, const float* W2, const float* b2,
                 float* emb, int col) {
    const int* src = edge;
    const int* dst = edge + m;
    hipMemsetAsync(dis, 0, (size_t)n * sizeof(float), stream);
    deg_scatter<<<ceil_div(m, 256), 256, 0, stream>>>(dst, attr, dis, m);
    finish_dis<<<ceil_div(n, 256), 256, 0, stream>>>(dis, n);
    // conv1
    gemm_f32<0><<<dim3(8, ceil_div(n, 64)), 256, 0, stream>>>(x, W1, hbuf, n, 512, 512, 512, 512, 512);
    hipMemsetAsync(agg, 0, (size_t)n * 512 * sizeof(float), stream);
    gcn_scatter<<<ceil_div(m * 128, 256), 256, 0, stream>>>(src, dst, attr, dis, hbuf, agg, m);
    gcn_epilogue<<<ceil_div(n * 512, 256), 256, 0, stream>>>(agg, hbuf, dis, b1, emb + col, n, 2048);
    // conv2 (input = relu'd conv1 living in emb, lda=2048)
    gemm_f32<0><<<dim3(8, ceil_div(n, 64)), 256, 0, stream>>>(emb + col, W2, hbuf, n, 512, 512, 2048, 512, 512);
    hipMemsetAsync(agg, 0, (size_t)n * 512 * sizeof(float), stream);
    gcn_scatter<<<ceil_div(m * 128, 256), 256, 0, stream>>>(src, dst, attr, dis, hbuf, agg, m);
    gcn_epilogue<<<ceil_div(n * 512, 256), 256, 0, stream>>>(agg, hbuf, dis, b2, emb + col + 512, n, 2048);
  };

  enc(mirna_x, NM, e_mm1, a_mm1, m_mm1, (const float*)d_in[10], (const float*)d_in[11],
      (const float*)d_in[12], (const float*)d_in[13], emb_m, 0);
  enc(mirna_x, NM, e_mm2, a_mm2, m_mm2, (const float*)d_in[14], (const float*)d_in[15],
      (const float*)d_in[16], (const float*)d_in[17], emb_m, 1024);
  enc(drug_x, ND, e_dd1, a_dd1, m_dd1, (const float*)d_in[18], (const float*)d_in[19],
      (const float*)d_in[20], (const float*)d_in[21], emb_d, 0);
  enc(drug_x, ND, e_dd2, a_dd2, m_dd2, (const float*)d_in[22], (const float*)d_in[23],
      (const float*)d_in[24], (const float*)d_in[25], emb_d, 1024);

  auto pipe = [&](float* emb, int n, const float* Wq, const float* Wk, const float* Wv,
                  const float* Wo, const float* fw, const float* fb,
                  float* xv, float* Qb, float* Kb, float* Vb, float* y) {
    gather_view<<<ceil_div(n * 2048, 256), 256, 0, stream>>>(emb, xv, n);
    const int M4 = 4 * n;
    dim3 gg(8, ceil_div(M4, 64));
    gemm_f32<0><<<gg, 256, 0, stream>>>(xv, Wq, Qb, M4, 512, 512, 512, 512, 512);
    gemm_f32<0><<<gg, 256, 0, stream>>>(xv, Wk, Kb, M4, 512, 512, 512, 512, 512);
    gemm_f32<0><<<gg, 256, 0, stream>>>(xv, Wv, Vb, M4, 512, 512, 512, 512, 512);
    // attention writes o2 into xv (xv no longer needed)
    attn_kernel<<<dim3(ceil_div(n, ATT_R), 32), 256, 0, stream>>>(Qb, Kb, Vb, xv, n);
    // mha = o2 @ Wo, into Qb (free now)
    gemm_f32<0><<<gg, 256, 0, stream>>>(xv, Wo, Qb, M4, 512, 512, 512, 512, 512);
    fuse_kernel<<<ceil_div(n * 512, 256), 256, 0, stream>>>(Qb, fw, fb, y, n);
  };

  pipe(emb_m, NM, (const float*)d_in[26], (const float*)d_in[27], (const float*)d_in[28],
       (const float*)d_in[29], (const float*)d_in[30], (const float*)d_in[31],
       xv_m, Qm, Km, Vm, y_m);
  pipe(emb_d, ND, (const float*)d_in[32], (const float*)d_in[33], (const float*)d_in[34],
       (const float*)d_in[35], (const float*)d_in[36], (const float*)d_in[37],
       xv_d, Qd, Kd, Vd, y_d);

  // final: out[i,j] = sum_k y_m[k*NM+i] * y_d[k*ND+j]   (TN gemm on flat views)
  gemm_f32<1><<<dim3(ceil_div(ND, 64), ceil_div(NM, 64)), 256, 0, stream>>>(
      y_m, y_d, out, NM, ND, 512, NM, ND, ND);
}

// Round 4
// 8022.757 us; speedup vs baseline: 1.2486x; 1.2486x over previous
//
#include <hip/hip_runtime.h>
#include <cmath>

#define NM 1043
#define ND 2166

static inline int ceil_div(int a, int b) { return (a + b - 1) / b; }

// ================= batched 64x64x512 GEMM, N=K=ldb=ldc=512 fixed =============
struct BGemm {
  const float* A[6]; const float* B[6]; float* C[6];
  int M[6]; int lda[6];
};

__global__ __launch_bounds__(256) void gemm_batched(BGemm g) {
  const int z = blockIdx.z;
  const int M = g.M[z];
  const int bm = blockIdx.y << 6;
  if (bm >= M) return;
  const int bn = blockIdx.x << 6;
  const int lda = g.lda[z];
  const float* __restrict__ A = g.A[z];
  const float* __restrict__ B = g.B[z];
  float* __restrict__ C = g.C[z];

  __shared__ float As[16][68];
  __shared__ float Bs[16][68];
  const int tid = threadIdx.x;
  const int tx = tid & 15, ty = tid >> 4;
  const int smm = tid >> 2, skq = tid & 3;   // A staging: row smm, k-quad skq
  const int skk = tid >> 4, snq = tid & 15;  // B staging: k-row skk, n-quad snq

  float acc[4][4] = {};
  for (int k0 = 0; k0 < 512; k0 += 16) {
    float4 af = make_float4(0.f, 0.f, 0.f, 0.f);
    if (bm + smm < M) af = *(const float4*)&A[(size_t)(bm + smm) * lda + k0 + 4 * skq];
    float4 bf = *(const float4*)&B[(size_t)(k0 + skk) * 512 + bn + 4 * snq];
    __syncthreads();  // previous-iter readers done before we overwrite
    As[4 * skq + 0][smm] = af.x;
    As[4 * skq + 1][smm] = af.y;
    As[4 * skq + 2][smm] = af.z;
    As[4 * skq + 3][smm] = af.w;
    *(float4*)&Bs[skk][4 * snq] = bf;
    __syncthreads();
#pragma unroll
    for (int kk = 0; kk < 16; kk++) {
      float4 a4 = *(const float4*)&As[kk][ty * 4];
      float4 b4 = *(const float4*)&Bs[kk][tx * 4];
      acc[0][0] += a4.x * b4.x; acc[0][1] += a4.x * b4.y; acc[0][2] += a4.x * b4.z; acc[0][3] += a4.x * b4.w;
      acc[1][0] += a4.y * b4.x; acc[1][1] += a4.y * b4.y; acc[1][2] += a4.y * b4.z; acc[1][3] += a4.y * b4.w;
      acc[2][0] += a4.z * b4.x; acc[2][1] += a4.z * b4.y; acc[2][2] += a4.z * b4.z; acc[2][3] += a4.z * b4.w;
      acc[3][0] += a4.w * b4.x; acc[3][1] += a4.w * b4.y; acc[3][2] += a4.w * b4.z; acc[3][3] += a4.w * b4.w;
    }
  }
#pragma unroll
  for (int i = 0; i < 4; i++) {
    int row = bm + ty * 4 + i;
    if (row < M) {
      float4 o = make_float4(acc[i][0], acc[i][1], acc[i][2], acc[i][3]);
      *(float4*)&C[(size_t)row * 512 + bn + tx * 4] = o;
    }
  }
}

// ================= final TN GEMM (layout-twist sensitive, scalar staging) ====
// C[M,N] = A^T-view @ B : A read as A[k*lda + m], B as B[k*ldb + n].
__global__ __launch_bounds__(256) void gemm_tn(
    const float* __restrict__ A, const float* __restrict__ B, float* __restrict__ C,
    int M, int N, int K, int lda, int ldb, int ldc) {
  __shared__ float As[16][65];
  __shared__ float Bs[16][65];
  const int tid = threadIdx.x;
  const int tx = tid & 15, ty = tid >> 4;
  const int bm = blockIdx.y << 6, bn = blockIdx.x << 6;
  float acc[4][4] = {};
  for (int k0 = 0; k0 < K; k0 += 16) {
    for (int i = tid; i < 16 * 64; i += 256) {
      int kk = i >> 6, mm = i & 63;
      int r = k0 + kk, c = bm + mm;
      As[kk][mm] = (r < K && c < M) ? A[(size_t)r * lda + c] : 0.f;
    }
    for (int i = tid; i < 16 * 64; i += 256) {
      int kk = i >> 6, nn = i & 63;
      int r = k0 + kk, c = bn + nn;
      Bs[kk][nn] = (r < K && c < N) ? B[(size_t)r * ldb + c] : 0.f;
    }
    __syncthreads();
#pragma unroll
    for (int kk = 0; kk < 16; kk++) {
      float a[4], b[4];
#pragma unroll
      for (int i = 0; i < 4; i++) a[i] = As[kk][ty + (i << 4)];
#pragma unroll
      for (int j = 0; j < 4; j++) b[j] = Bs[kk][tx + (j << 4)];
#pragma unroll
      for (int i = 0; i < 4; i++)
#pragma unroll
        for (int j = 0; j < 4; j++) acc[i][j] += a[i] * b[j];
    }
    __syncthreads();
  }
#pragma unroll
  for (int i = 0; i < 4; i++) {
    int r = bm + ty + (i << 4);
    if (r >= M) continue;
#pragma unroll
    for (int j = 0; j < 4; j++) {
      int c = bn + tx + (j << 4);
      if (c < N) C[(size_t)r * ldc + c] = acc[i][j];
    }
  }
}

// ================= GCN batched pieces =================
struct GraphB {
  const int* src[4]; const int* dst[4]; const float* attr[4];
  float* dis[4]; const float* h[4]; float* agg[4];
  int m[4]; int n[4]; int epref[5];
};

__global__ __launch_bounds__(256) void deg_b(GraphB g) {
  int z = blockIdx.z;
  int e = blockIdx.x * 256 + threadIdx.x;
  if (e < g.m[z]) atomicAdd(&g.dis[z][g.dst[z][e]], g.attr[z][e]);
}

__global__ __launch_bounds__(256) void finish_dis_b(GraphB g) {
  int z = blockIdx.z;
  int i = blockIdx.x * 256 + threadIdx.x;
  if (i < g.n[z]) g.dis[z][i] = rsqrtf(g.dis[z][i] + 1.0f);  // +1 self-loop
}

// flattened over all 4 graphs: 128 threads/edge, 4 floats/thread
__global__ __launch_bounds__(256) void gcn_scatter_b(GraphB g) {
  long long t = (long long)blockIdx.x * 256 + threadIdx.x;
  int et = (int)(t >> 7);
  if (et >= g.epref[4]) return;
  int z = (et >= g.epref[1]) + (et >= g.epref[2]) + (et >= g.epref[3]);
  int e = et - g.epref[z];
  int f = ((int)t & 127) << 2;
  int s = g.src[z][e], d = g.dst[z][e];
  float nrm = g.dis[z][s] * g.attr[z][e] * g.dis[z][d];
  const float4 hv = *(const float4*)&g.h[z][((size_t)s << 9) + f];
  float* ap = g.agg[z] + ((size_t)d << 9) + f;
  atomicAdd(ap + 0, nrm * hv.x);
  atomicAdd(ap + 1, nrm * hv.y);
  atomicAdd(ap + 2, nrm * hv.z);
  atomicAdd(ap + 3, nrm * hv.w);
}

struct EpiB {
  const float* agg[4]; const float* h[4]; const float* dis[4]; const float* b[4];
  float* out[4]; int n[4];
};

__global__ __launch_bounds__(256) void gcn_epilogue_b(EpiB e) {
  int z = blockIdx.z;
  int i = blockIdx.x * 256 + threadIdx.x;
  if (i >= e.n[z] * 512) return;
  int node = i >> 9, f = i & 511;
  float di = e.dis[z][node];
  float v = e.agg[z][i] + di * di * e.h[z][i] + e.b[z][f];
  e.out[z][(size_t)node * 2048 + f] = fmaxf(v, 0.f);
}

// ================= view gather =================
struct GatherB { const float* emb[2]; float* xv[2]; int n[2]; };

__global__ __launch_bounds__(256) void gather_b(GatherB g) {
  int z = blockIdx.z;
  int n = g.n[z];
  size_t i = (size_t)blockIdx.x * 256 + threadIdx.x;
  if (i >= (size_t)n * 2048) return;
  int e = (int)(i & 511);
  size_t t = i >> 9;  // v*n + nn
  int v = (int)(t / n);
  int nn = (int)(t - (size_t)v * n);
  g.xv[z][i] = g.emb[z][((size_t)v * 512 + e) * n + nn];
}

// ================= attention v2: K-in-registers, float4 LDS =================
struct AttArgs { const float* Q[2]; const float* K[2]; const float* V[2]; float* O[2]; int N[2]; };

#define ATT_RW 8
__global__ __launch_bounds__(256) void attn2_kernel(AttArgs ar) {
  const int z = blockIdx.z;
  const int N = ar.N[z];
  const int rowbase = blockIdx.x * 32;
  if (rowbase >= N) return;
  const int vh = blockIdx.y, v = vh >> 3, h = vh & 7;
  const size_t base = (size_t)v * N * 512 + h * 64;
  const float* __restrict__ Qb = ar.Q[z] + base;
  const float* __restrict__ Kb = ar.K[z] + base;
  const float* __restrict__ Vb = ar.V[z] + base;
  float* __restrict__ Ob = ar.O[z] + base;

  __shared__ float kt[64][68];
  __shared__ float vt[64][68];
  __shared__ float qs[32][68];
  __shared__ float ps[32][64];

  const int tid = threadIdx.x, lane = tid & 63, w = tid >> 6;

  // stage q scaled by 1/sqrt(64): 32 rows x 16 quads
#pragma unroll
  for (int it = 0; it < 2; it++) {
    int q = tid + it * 256;
    int r = q >> 4, dq = q & 15;
    int row = rowbase + r;
    float4 f = make_float4(0.f, 0.f, 0.f, 0.f);
    if (row < N) f = *(const float4*)&Qb[(size_t)row * 512 + 4 * dq];
    qs[r][4 * dq + 0] = f.x * 0.125f;
    qs[r][4 * dq + 1] = f.y * 0.125f;
    qs[r][4 * dq + 2] = f.z * 0.125f;
    qs[r][4 * dq + 3] = f.w * 0.125f;
  }

  float rm[ATT_RW], rs[ATT_RW], oa[ATT_RW];
#pragma unroll
  for (int r = 0; r < ATT_RW; r++) { rm[r] = -INFINITY; rs[r] = 0.f; oa[r] = 0.f; }

  const int nt = (N + 63) >> 6;
  for (int mt = 0; mt < nt; mt++) {
    const int mb = mt << 6;
    __syncthreads();  // prior tile fully consumed (also covers qs on first iter)
#pragma unroll
    for (int it = 0; it < 4; it++) {
      int q = tid + it * 256;
      int m = q >> 4, dq = q & 15;
      int gm = mb + m;
      float4 kf = make_float4(0.f, 0.f, 0.f, 0.f);
      float4 vf = make_float4(0.f, 0.f, 0.f, 0.f);
      if (gm < N) {
        kf = *(const float4*)&Kb[(size_t)gm * 512 + 4 * dq];
        vf = *(const float4*)&Vb[(size_t)gm * 512 + 4 * dq];
      }
      *(float4*)&kt[m][4 * dq] = kf;
      *(float4*)&vt[m][4 * dq] = vf;
    }
    __syncthreads();

    // this lane's K row -> 16 float4 regs (reused across 8 q-rows)
    float4 kr[16];
#pragma unroll
    for (int d4 = 0; d4 < 16; d4++) kr[d4] = *(const float4*)&kt[lane][4 * d4];
    const bool mvalid = (mb + lane) < N;

#pragma unroll
    for (int r = 0; r < ATT_RW; r++) {
      const int qr = w * ATT_RW + r;
      float s = 0.f;
#pragma unroll
      for (int d4 = 0; d4 < 16; d4++) {
        float4 q4 = *(const float4*)&qs[qr][4 * d4];  // uniform-address broadcast
        s += q4.x * kr[d4].x + q4.y * kr[d4].y + q4.z * kr[d4].z + q4.w * kr[d4].w;
      }
      if (!mvalid) s = -INFINITY;
      float tmax = s;
      for (int off = 32; off; off >>= 1) tmax = fmaxf(tmax, __shfl_xor(tmax, off));
      float nm2 = fmaxf(rm[r], tmax);
      float sc = __expf(rm[r] - nm2);
      float pv = __expf(s - nm2);
      float ts = pv;
      for (int off = 32; off; off >>= 1) ts += __shfl_xor(ts, off);
      rs[r] = rs[r] * sc + ts;
      rm[r] = nm2;
      oa[r] *= sc;
      ps[qr][lane] = pv;  // wave-private rows, hw-ordered w.r.t. reads below
    }

    // PV: lane = output dim
#pragma unroll 4
    for (int l4 = 0; l4 < 16; l4++) {
      float vv0 = vt[4 * l4 + 0][lane];
      float vv1 = vt[4 * l4 + 1][lane];
      float vv2 = vt[4 * l4 + 2][lane];
      float vv3 = vt[4 * l4 + 3][lane];
#pragma unroll
      for (int r = 0; r < ATT_RW; r++) {
        float4 p4 = *(const float4*)&ps[w * ATT_RW + r][4 * l4];  // broadcast
        oa[r] += p4.x * vv0 + p4.y * vv1 + p4.z * vv2 + p4.w * vv3;
      }
    }
  }

#pragma unroll
  for (int r = 0; r < ATT_RW; r++) {
    int row = rowbase + w * ATT_RW + r;
    if (row < N) Ob[(size_t)row * 512 + lane] = oa[r] / rs[r];
  }
}

// ================= fuse =================
struct FuseB { const float* mha[2]; const float* fw[2]; const float* fb[2]; float* y[2]; int n[2]; };

__global__ __launch_bounds__(256) void fuse_b(FuseB fz) {
  int z = blockIdx.z;
  int n = fz.n[z];
  int i = blockIdx.x * 256 + threadIdx.x;
  if (i >= n * 512) return;
  size_t stride = (size_t)n * 512;
  const float* m = fz.mha[z];
  const float* fw = fz.fw[z];
  float acc = fz.fb[z][0];
  acc += fw[0] * m[i];
  acc += fw[1] * m[stride + i];
  acc += fw[2] * m[2 * stride + i];
  acc += fw[3] * m[3 * stride + i];
  fz.y[z][i] = acc;
}

// ================= launch =================
extern "C" void kernel_launch(void* const* d_in, const int* in_sizes, int n_in,
                              void* d_out, int out_size, void* d_ws, size_t ws_size,
                              hipStream_t stream) {
  const float* mirna_x = (const float*)d_in[0];
  const float* drug_x  = (const float*)d_in[1];
  const int* edge[4] = { (const int*)d_in[2], (const int*)d_in[4], (const int*)d_in[6], (const int*)d_in[8] };
  const float* attr[4] = { (const float*)d_in[3], (const float*)d_in[5], (const float*)d_in[7], (const float*)d_in[9] };
  const int m[4] = { in_sizes[2] / 2, in_sizes[4] / 2, in_sizes[6] / 2, in_sizes[8] / 2 };
  const int nn4[4] = { NM, NM, ND, ND };
  float* out = (float*)d_out;

  // -------- workspace carve --------
  float* ws = (float*)d_ws;
  size_t off = 0;
  auto take = [&](size_t nelem) {
    float* r = ws + off;
    off += (nelem + 255) & ~(size_t)255;
    return r;
  };
  const size_t HN = (size_t)NM * 512, HD = (size_t)ND * 512;
  const size_t HALL = 2 * HN + 2 * HD;  // 3,286,016
  float* emb_m = take((size_t)NM * 2048);
  float* emb_d = take((size_t)ND * 2048);
  float* region = take(2 * HALL);  // phase1: h(4)+agg(4); phase2: xv_m+xv_d
  float* h4[4]   = { region, region + HN, region + 2 * HN, region + 2 * HN + HD };
  float* agg4[4] = { region + HALL, region + HALL + HN, region + HALL + 2 * HN, region + HALL + 2 * HN + HD };
  float* xv_m = region;
  float* xv_d = region + (size_t)NM * 2048;
  float* dis_all = take(4 * 2560);
  float* dis4[4] = { dis_all, dis_all + 2560, dis_all + 2 * 2560, dis_all + 3 * 2560 };
  float* Qm = take((size_t)NM * 2048);
  float* Km = take((size_t)NM * 2048);
  float* Vm = take((size_t)NM * 2048);
  float* Qd = take((size_t)ND * 2048);
  float* Kd = take((size_t)ND * 2048);
  float* Vd = take((size_t)ND * 2048);
  float* y_m = take(HN);
  float* y_d = take(HD);

  // -------- graph struct --------
  GraphB gb;
  int pref = 0;
  for (int z = 0; z < 4; z++) {
    gb.src[z] = edge[z]; gb.dst[z] = edge[z] + m[z]; gb.attr[z] = attr[z];
    gb.dis[z] = dis4[z]; gb.h[z] = h4[z]; gb.agg[z] = agg4[z];
    gb.m[z] = m[z]; gb.n[z] = nn4[z];
    gb.epref[z] = pref; pref += m[z];
  }
  gb.epref[4] = pref;
  int mmax = 0;
  for (int z = 0; z < 4; z++) mmax = m[z] > mmax ? m[z] : mmax;

  // -------- degree + norm --------
  hipMemsetAsync(dis_all, 0, 4 * 2560 * sizeof(float), stream);
  deg_b<<<dim3(ceil_div(mmax, 256), 1, 4), 256, 0, stream>>>(gb);
  finish_dis_b<<<dim3(ceil_div(ND, 256), 1, 4), 256, 0, stream>>>(gb);

  // -------- conv1 --------
  BGemm c1;
  const float* xin[4] = { mirna_x, mirna_x, drug_x, drug_x };
  for (int z = 0; z < 4; z++) {
    c1.A[z] = xin[z]; c1.B[z] = (const float*)d_in[10 + 4 * z]; c1.C[z] = h4[z];
    c1.M[z] = nn4[z]; c1.lda[z] = 512;
  }
  for (int z = 4; z < 6; z++) { c1.A[z] = nullptr; c1.B[z] = nullptr; c1.C[z] = nullptr; c1.M[z] = 0; c1.lda[z] = 512; }
  gemm_batched<<<dim3(8, ceil_div(ND, 64), 4), 256, 0, stream>>>(c1);

  hipMemsetAsync(region + HALL, 0, HALL * sizeof(float), stream);  // aggs
  int sblocks = ceil_div(pref * 128, 256);
  gcn_scatter_b<<<dim3(sblocks, 1, 1), 256, 0, stream>>>(gb);

  EpiB e1;
  float* embp[4] = { emb_m, emb_m + 1024, emb_d, emb_d + 1024 };
  for (int z = 0; z < 4; z++) {
    e1.agg[z] = agg4[z]; e1.h[z] = h4[z]; e1.dis[z] = dis4[z];
    e1.b[z] = (const float*)d_in[11 + 4 * z]; e1.out[z] = embp[z]; e1.n[z] = nn4[z];
  }
  gcn_epilogue_b<<<dim3(ceil_div(ND * 512, 256), 1, 4), 256, 0, stream>>>(e1);

  // -------- conv2 --------
  BGemm c2 = c1;
  for (int z = 0; z < 4; z++) {
    c2.A[z] = embp[z]; c2.B[z] = (const float*)d_in[12 + 4 * z]; c2.C[z] = h4[z];
    c2.M[z] = nn4[z]; c2.lda[z] = 2048;
  }
  gemm_batched<<<dim3(8, ceil_div(ND, 64), 4), 256, 0, stream>>>(c2);

  hipMemsetAsync(region + HALL, 0, HALL * sizeof(float), stream);
  gcn_scatter_b<<<dim3(sblocks, 1, 1), 256, 0, stream>>>(gb);

  EpiB e2 = e1;
  for (int z = 0; z < 4; z++) { e2.b[z] = (const float*)d_in[13 + 4 * z]; e2.out[z] = embp[z] + 512; }
  gcn_epilogue_b<<<dim3(ceil_div(ND * 512, 256), 1, 4), 256, 0, stream>>>(e2);

  // -------- gather (overwrites h/agg region) --------
  GatherB gt;
  gt.emb[0] = emb_m; gt.emb[1] = emb_d; gt.xv[0] = xv_m; gt.xv[1] = xv_d;
  gt.n[0] = NM; gt.n[1] = ND;
  gather_b<<<dim3(ceil_div(ND * 2048, 256), 1, 2), 256, 0, stream>>>(gt);

  // -------- QKV projections (z=6) --------
  BGemm qkv;
  const float* wq[6] = { (const float*)d_in[26], (const float*)d_in[27], (const float*)d_in[28],
                         (const float*)d_in[32], (const float*)d_in[33], (const float*)d_in[34] };
  float* qkvc[6] = { Qm, Km, Vm, Qd, Kd, Vd };
  for (int z = 0; z < 6; z++) {
    qkv.A[z] = (z < 3) ? xv_m : xv_d; qkv.B[z] = wq[z]; qkv.C[z] = qkvc[z];
    qkv.M[z] = (z < 3) ? 4 * NM : 4 * ND; qkv.lda[z] = 512;
  }
  gemm_batched<<<dim3(8, ceil_div(4 * ND, 64), 6), 256, 0, stream>>>(qkv);

  // -------- attention (o2 -> xv buffers) --------
  AttArgs aa;
  aa.Q[0] = Qm; aa.K[0] = Km; aa.V[0] = Vm; aa.O[0] = xv_m; aa.N[0] = NM;
  aa.Q[1] = Qd; aa.K[1] = Kd; aa.V[1] = Vd; aa.O[1] = xv_d; aa.N[1] = ND;
  attn2_kernel<<<dim3(ceil_div(ND, 32), 32, 2), 256, 0, stream>>>(aa);

  // -------- Wo (mha -> Qm/Qd) --------
  BGemm wo;
  for (int z = 0; z < 2; z++) {
    wo.A[z] = (z == 0) ? xv_m : xv_d;
    wo.B[z] = (const float*)d_in[z == 0 ? 29 : 35];
    wo.C[z] = (z == 0) ? Qm : Qd;
    wo.M[z] = (z == 0) ? 4 * NM : 4 * ND; wo.lda[z] = 512;
  }
  for (int z = 2; z < 6; z++) { wo.A[z] = nullptr; wo.B[z] = nullptr; wo.C[z] = nullptr; wo.M[z] = 0; wo.lda[z] = 512; }
  gemm_batched<<<dim3(8, ceil_div(4 * ND, 64), 2), 256, 0, stream>>>(wo);

  // -------- fuse --------
  FuseB fz;
  fz.mha[0] = Qm; fz.mha[1] = Qd;
  fz.fw[0] = (const float*)d_in[30]; fz.fw[1] = (const float*)d_in[36];
  fz.fb[0] = (const float*)d_in[31]; fz.fb[1] = (const float*)d_in[37];
  fz.y[0] = y_m; fz.y[1] = y_d;
  fz.n[0] = NM; fz.n[1] = ND;
  fuse_b<<<dim3(ceil_div(ND * 512, 256), 1, 2), 256, 0, stream>>>(fz);

  // -------- final: out[i,j] = sum_k y_m[k*NM+i] * y_d[k*ND+j] --------
  gemm_tn<<<dim3(ceil_div(ND, 64), ceil_div(NM, 64)), 256, 0, stream>>>(
      y_m, y_d, out, NM, ND, 512, NM, ND, ND);
}

// Round 5
// 2560.368 us; speedup vs baseline: 3.9125x; 3.1334x over previous
//
#include <hip/hip_runtime.h>
#include <cmath>

#define NM 1043
#define ND 2166

static inline int ceil_div(int a, int b) { return (a + b - 1) / b; }

// ================= batched 64x64x512 GEMM, N=K=ldb=ldc=512 fixed =============
struct BGemm {
  const float* A[6]; const float* B[6]; float* C[6];
  int M[6]; int lda[6];
};

__global__ __launch_bounds__(256) void gemm_batched(BGemm g) {
  const int z = blockIdx.z;
  const int M = g.M[z];
  const int bm = blockIdx.y << 6;
  if (bm >= M) return;
  const int bn = blockIdx.x << 6;
  const int lda = g.lda[z];
  const float* __restrict__ A = g.A[z];
  const float* __restrict__ B = g.B[z];
  float* __restrict__ C = g.C[z];

  __shared__ float As[16][68];
  __shared__ float Bs[16][68];
  const int tid = threadIdx.x;
  const int tx = tid & 15, ty = tid >> 4;
  const int smm = tid >> 2, skq = tid & 3;   // A staging: row smm, k-quad skq
  const int skk = tid >> 4, snq = tid & 15;  // B staging: k-row skk, n-quad snq

  float acc[4][4] = {};
  for (int k0 = 0; k0 < 512; k0 += 16) {
    float4 af = make_float4(0.f, 0.f, 0.f, 0.f);
    if (bm + smm < M) af = *(const float4*)&A[(size_t)(bm + smm) * lda + k0 + 4 * skq];
    float4 bf = *(const float4*)&B[(size_t)(k0 + skk) * 512 + bn + 4 * snq];
    __syncthreads();  // previous-iter readers done before we overwrite
    As[4 * skq + 0][smm] = af.x;
    As[4 * skq + 1][smm] = af.y;
    As[4 * skq + 2][smm] = af.z;
    As[4 * skq + 3][smm] = af.w;
    *(float4*)&Bs[skk][4 * snq] = bf;
    __syncthreads();
#pragma unroll
    for (int kk = 0; kk < 16; kk++) {
      float4 a4 = *(const float4*)&As[kk][ty * 4];
      float4 b4 = *(const float4*)&Bs[kk][tx * 4];
      acc[0][0] += a4.x * b4.x; acc[0][1] += a4.x * b4.y; acc[0][2] += a4.x * b4.z; acc[0][3] += a4.x * b4.w;
      acc[1][0] += a4.y * b4.x; acc[1][1] += a4.y * b4.y; acc[1][2] += a4.y * b4.z; acc[1][3] += a4.y * b4.w;
      acc[2][0] += a4.z * b4.x; acc[2][1] += a4.z * b4.y; acc[2][2] += a4.z * b4.z; acc[2][3] += a4.z * b4.w;
      acc[3][0] += a4.w * b4.x; acc[3][1] += a4.w * b4.y; acc[3][2] += a4.w * b4.z; acc[3][3] += a4.w * b4.w;
    }
  }
#pragma unroll
  for (int i = 0; i < 4; i++) {
    int row = bm + ty * 4 + i;
    if (row < M) {
      float4 o = make_float4(acc[i][0], acc[i][1], acc[i][2], acc[i][3]);
      *(float4*)&C[(size_t)row * 512 + bn + tx * 4] = o;
    }
  }
}

// ================= final TN GEMM (layout-twist sensitive, scalar staging) ====
__global__ __launch_bounds__(256) void gemm_tn(
    const float* __restrict__ A, const float* __restrict__ B, float* __restrict__ C,
    int M, int N, int K, int lda, int ldb, int ldc) {
  __shared__ float As[16][65];
  __shared__ float Bs[16][65];
  const int tid = threadIdx.x;
  const int tx = tid & 15, ty = tid >> 4;
  const int bm = blockIdx.y << 6, bn = blockIdx.x << 6;
  float acc[4][4] = {};
  for (int k0 = 0; k0 < K; k0 += 16) {
    for (int i = tid; i < 16 * 64; i += 256) {
      int kk = i >> 6, mm = i & 63;
      int r = k0 + kk, c = bm + mm;
      As[kk][mm] = (r < K && c < M) ? A[(size_t)r * lda + c] : 0.f;
    }
    for (int i = tid; i < 16 * 64; i += 256) {
      int kk = i >> 6, nn = i & 63;
      int r = k0 + kk, c = bn + nn;
      Bs[kk][nn] = (r < K && c < N) ? B[(size_t)r * ldb + c] : 0.f;
    }
    __syncthreads();
#pragma unroll
    for (int kk = 0; kk < 16; kk++) {
      float a[4], b[4];
#pragma unroll
      for (int i = 0; i < 4; i++) a[i] = As[kk][ty + (i << 4)];
#pragma unroll
      for (int j = 0; j < 4; j++) b[j] = Bs[kk][tx + (j << 4)];
#pragma unroll
      for (int i = 0; i < 4; i++)
#pragma unroll
        for (int j = 0; j < 4; j++) acc[i][j] += a[i] * b[j];
    }
    __syncthreads();
  }
#pragma unroll
  for (int i = 0; i < 4; i++) {
    int r = bm + ty + (i << 4);
    if (r >= M) continue;
#pragma unroll
    for (int j = 0; j < 4; j++) {
      int c = bn + tx + (j << 4);
      if (c < N) C[(size_t)r * ldc + c] = acc[i][j];
    }
  }
}

// ================= GCN: CSR build + fused gather =================
struct DegB {
  const int* dst[4]; const float* attr[4];
  float* dis[4]; int* cnt[4];
  int epref[5];
};

__global__ __launch_bounds__(256) void deg_count_b(DegB g) {
  int et = blockIdx.x * 256 + threadIdx.x;
  if (et >= g.epref[4]) return;
  int z = (et >= g.epref[1]) + (et >= g.epref[2]) + (et >= g.epref[3]);
  int e = et - g.epref[z];
  int d = g.dst[z][e];
  atomicAdd(&g.dis[z][d], g.attr[z][e]);
  atomicAdd(&g.cnt[z][d], 1);
}

struct FinB { float* dis[4]; int n[4]; };

__global__ __launch_bounds__(256) void finish_dis_b(FinB g) {
  int z = blockIdx.z;
  int i = blockIdx.x * 256 + threadIdx.x;
  if (i < g.n[z]) g.dis[z][i] = rsqrtf(g.dis[z][i] + 1.0f);  // +1 self-loop
}

struct ScanB { const int* cnt[4]; int* rowptr[4]; int n[4]; };

// one block per graph: exclusive scan of cnt -> rowptr[0..n], rowptr[n]=total
__global__ __launch_bounds__(256) void scan_b(ScanB s) {
  int z = blockIdx.x;
  int n = s.n[z];
  const int* cnt = s.cnt[z];
  int* rp = s.rowptr[z];
  __shared__ int sums[256];
  int tid = threadIdx.x;
  int chunk = (n + 255) >> 8;
  int start = tid * chunk;
  int local = 0;
  for (int i = 0; i < chunk; i++) {
    int idx = start + i;
    if (idx < n) local += cnt[idx];
  }
  sums[tid] = local;
  __syncthreads();
  for (int off = 1; off < 256; off <<= 1) {
    int t = (tid >= off) ? sums[tid - off] : 0;
    __syncthreads();
    sums[tid] += t;
    __syncthreads();
  }
  int base = sums[tid] - local;  // exclusive prefix for this chunk
  int total = sums[255];
  int run = base;
  for (int i = 0; i < chunk; i++) {
    int idx = start + i;
    if (idx < n) { rp[idx] = run; run += cnt[idx]; }
  }
  if (tid == 0) rp[n] = total;
}

struct FillB {
  const int* src[4]; const int* dst[4]; const float* attr[4];
  const int* rowptr[4]; int* cur[4]; int* col[4]; float* val[4];
  int epref[5];
};

__global__ __launch_bounds__(256) void fill_b(FillB f) {
  int et = blockIdx.x * 256 + threadIdx.x;
  if (et >= f.epref[4]) return;
  int z = (et >= f.epref[1]) + (et >= f.epref[2]) + (et >= f.epref[3]);
  int e = et - f.epref[z];
  int d = f.dst[z][e];
  int pos = f.rowptr[z][d] + atomicAdd(&f.cur[z][d], 1);
  f.col[z][pos] = f.src[z][e];
  f.val[z][pos] = f.attr[z][e];
}

// fused gather + self-loop + bias + relu, writes emb (stride 2048)
struct GathB {
  const int* rowptr[4]; const int* col[4]; const float* val[4];
  const float* dis[4]; const float* h[4]; const float* b[4];
  float* out[4]; int n[4];
};

__global__ __launch_bounds__(256) void gcn_gather_b(GathB c) {
  const int z = blockIdx.z;
  const int node = blockIdx.x;
  if (node >= c.n[z]) return;
  const int tid = threadIdx.x;
  const int* __restrict__ col = c.col[z];
  const float* __restrict__ val = c.val[z];
  const float* __restrict__ dis = c.dis[z];
  const float* __restrict__ h = c.h[z];
  const int beg = c.rowptr[z][node], end = c.rowptr[z][node + 1];
  float acc0 = 0.f, acc1 = 0.f;
  int e = beg;
  for (; e + 4 <= end; e += 4) {
    int s0 = col[e], s1 = col[e + 1], s2 = col[e + 2], s3 = col[e + 3];
    float w0 = val[e] * dis[s0];
    float w1 = val[e + 1] * dis[s1];
    float w2 = val[e + 2] * dis[s2];
    float w3 = val[e + 3] * dis[s3];
    const float* p0 = h + ((size_t)s0 << 9);
    const float* p1 = h + ((size_t)s1 << 9);
    const float* p2 = h + ((size_t)s2 << 9);
    const float* p3 = h + ((size_t)s3 << 9);
    acc0 += w0 * p0[tid] + w1 * p1[tid] + w2 * p2[tid] + w3 * p3[tid];
    acc1 += w0 * p0[tid + 256] + w1 * p1[tid + 256] + w2 * p2[tid + 256] + w3 * p3[tid + 256];
  }
  for (; e < end; e++) {
    int s = col[e];
    float w = val[e] * dis[s];
    const float* p = h + ((size_t)s << 9);
    acc0 += w * p[tid];
    acc1 += w * p[tid + 256];
  }
  const float dd = dis[node];
  const float* hp = h + ((size_t)node << 9);
  float o0 = fmaxf(dd * acc0 + dd * dd * hp[tid] + c.b[z][tid], 0.f);
  float o1 = fmaxf(dd * acc1 + dd * dd * hp[tid + 256] + c.b[z][tid + 256], 0.f);
  float* op = c.out[z] + (size_t)node * 2048;
  op[tid] = o0;
  op[tid + 256] = o1;
}

// ================= view gather =================
struct GatherB { const float* emb[2]; float* xv[2]; int n[2]; };

__global__ __launch_bounds__(256) void gather_b(GatherB g) {
  int z = blockIdx.z;
  int n = g.n[z];
  size_t i = (size_t)blockIdx.x * 256 + threadIdx.x;
  if (i >= (size_t)n * 2048) return;
  int e = (int)(i & 511);
  size_t t = i >> 9;  // v*n + nn
  int v = (int)(t / n);
  int nn = (int)(t - (size_t)v * n);
  g.xv[z][i] = g.emb[z][((size_t)v * 512 + e) * n + nn];
}

// ================= attention v2: K-in-registers, float4 LDS =================
struct AttArgs { const float* Q[2]; const float* K[2]; const float* V[2]; float* O[2]; int N[2]; };

#define ATT_RW 8
__global__ __launch_bounds__(256) void attn2_kernel(AttArgs ar) {
  const int z = blockIdx.z;
  const int N = ar.N[z];
  const int rowbase = blockIdx.x * 32;
  if (rowbase >= N) return;
  const int vh = blockIdx.y, v = vh >> 3, h = vh & 7;
  const size_t base = (size_t)v * N * 512 + h * 64;
  const float* __restrict__ Qb = ar.Q[z] + base;
  const float* __restrict__ Kb = ar.K[z] + base;
  const float* __restrict__ Vb = ar.V[z] + base;
  float* __restrict__ Ob = ar.O[z] + base;

  __shared__ float kt[64][68];
  __shared__ float vt[64][68];
  __shared__ float qs[32][68];
  __shared__ float ps[32][64];

  const int tid = threadIdx.x, lane = tid & 63, w = tid >> 6;

#pragma unroll
  for (int it = 0; it < 2; it++) {
    int q = tid + it * 256;
    int r = q >> 4, dq = q & 15;
    int row = rowbase + r;
    float4 f = make_float4(0.f, 0.f, 0.f, 0.f);
    if (row < N) f = *(const float4*)&Qb[(size_t)row * 512 + 4 * dq];
    qs[r][4 * dq + 0] = f.x * 0.125f;
    qs[r][4 * dq + 1] = f.y * 0.125f;
    qs[r][4 * dq + 2] = f.z * 0.125f;
    qs[r][4 * dq + 3] = f.w * 0.125f;
  }

  float rm[ATT_RW], rs[ATT_RW], oa[ATT_RW];
#pragma unroll
  for (int r = 0; r < ATT_RW; r++) { rm[r] = -INFINITY; rs[r] = 0.f; oa[r] = 0.f; }

  const int nt = (N + 63) >> 6;
  for (int mt = 0; mt < nt; mt++) {
    const int mb = mt << 6;
    __syncthreads();
#pragma unroll
    for (int it = 0; it < 4; it++) {
      int q = tid + it * 256;
      int m = q >> 4, dq = q & 15;
      int gm = mb + m;
      float4 kf = make_float4(0.f, 0.f, 0.f, 0.f);
      float4 vf = make_float4(0.f, 0.f, 0.f, 0.f);
      if (gm < N) {
        kf = *(const float4*)&Kb[(size_t)gm * 512 + 4 * dq];
        vf = *(const float4*)&Vb[(size_t)gm * 512 + 4 * dq];
      }
      *(float4*)&kt[m][4 * dq] = kf;
      *(float4*)&vt[m][4 * dq] = vf;
    }
    __syncthreads();

    float4 kr[16];
#pragma unroll
    for (int d4 = 0; d4 < 16; d4++) kr[d4] = *(const float4*)&kt[lane][4 * d4];
    const bool mvalid = (mb + lane) < N;

#pragma unroll
    for (int r = 0; r < ATT_RW; r++) {
      const int qr = w * ATT_RW + r;
      float s = 0.f;
#pragma unroll
      for (int d4 = 0; d4 < 16; d4++) {
        float4 q4 = *(const float4*)&qs[qr][4 * d4];  // uniform-address broadcast
        s += q4.x * kr[d4].x + q4.y * kr[d4].y + q4.z * kr[d4].z + q4.w * kr[d4].w;
      }
      if (!mvalid) s = -INFINITY;
      float tmax = s;
      for (int off = 32; off; off >>= 1) tmax = fmaxf(tmax, __shfl_xor(tmax, off));
      float nm2 = fmaxf(rm[r], tmax);
      float sc = __expf(rm[r] - nm2);
      float pv = __expf(s - nm2);
      float ts = pv;
      for (int off = 32; off; off >>= 1) ts += __shfl_xor(ts, off);
      rs[r] = rs[r] * sc + ts;
      rm[r] = nm2;
      oa[r] *= sc;
      ps[qr][lane] = pv;  // wave-private rows, hw-ordered w.r.t. reads below
    }

#pragma unroll 4
    for (int l4 = 0; l4 < 16; l4++) {
      float vv0 = vt[4 * l4 + 0][lane];
      float vv1 = vt[4 * l4 + 1][lane];
      float vv2 = vt[4 * l4 + 2][lane];
      float vv3 = vt[4 * l4 + 3][lane];
#pragma unroll
      for (int r = 0; r < ATT_RW; r++) {
        float4 p4 = *(const float4*)&ps[w * ATT_RW + r][4 * l4];  // broadcast
        oa[r] += p4.x * vv0 + p4.y * vv1 + p4.z * vv2 + p4.w * vv3;
      }
    }
  }

#pragma unroll
  for (int r = 0; r < ATT_RW; r++) {
    int row = rowbase + w * ATT_RW + r;
    if (row < N) Ob[(size_t)row * 512 + lane] = oa[r] / rs[r];
  }
}

// ================= fuse =================
struct FuseB { const float* mha[2]; const float* fw[2]; const float* fb[2]; float* y[2]; int n[2]; };

__global__ __launch_bounds__(256) void fuse_b(FuseB fz) {
  int z = blockIdx.z;
  int n = fz.n[z];
  int i = blockIdx.x * 256 + threadIdx.x;
  if (i >= n * 512) return;
  size_t stride = (size_t)n * 512;
  const float* m = fz.mha[z];
  const float* fw = fz.fw[z];
  float acc = fz.fb[z][0];
  acc += fw[0] * m[i];
  acc += fw[1] * m[stride + i];
  acc += fw[2] * m[2 * stride + i];
  acc += fw[3] * m[3 * stride + i];
  fz.y[z][i] = acc;
}

// ================= launch =================
extern "C" void kernel_launch(void* const* d_in, const int* in_sizes, int n_in,
                              void* d_out, int out_size, void* d_ws, size_t ws_size,
                              hipStream_t stream) {
  const float* mirna_x = (const float*)d_in[0];
  const float* drug_x  = (const float*)d_in[1];
  const int* edge[4] = { (const int*)d_in[2], (const int*)d_in[4], (const int*)d_in[6], (const int*)d_in[8] };
  const float* attr[4] = { (const float*)d_in[3], (const float*)d_in[5], (const float*)d_in[7], (const float*)d_in[9] };
  const int m[4] = { in_sizes[2] / 2, in_sizes[4] / 2, in_sizes[6] / 2, in_sizes[8] / 2 };
  const int nn4[4] = { NM, NM, ND, ND };
  float* out = (float*)d_out;

  // -------- workspace carve --------
  float* ws = (float*)d_ws;
  size_t off = 0;
  auto take = [&](size_t nelem) {
    float* r = ws + off;
    off += (nelem + 255) & ~(size_t)255;
    return r;
  };
  const size_t HN = (size_t)NM * 512, HD = (size_t)ND * 512;
  const size_t HALL = 2 * HN + 2 * HD;
  float* emb_m = take((size_t)NM * 2048);
  float* emb_d = take((size_t)ND * 2048);
  float* region = take(2 * HALL);  // phase1: h4; phase2: xv_m+xv_d
  float* h4[4] = { region, region + HN, region + 2 * HN, region + 2 * HN + HD };
  float* xv_m = region;
  float* xv_d = region + (size_t)NM * 2048;
  float* dis_all = take(4 * 2560);
  float* dis4[4] = { dis_all, dis_all + 2560, dis_all + 2 * 2560, dis_all + 3 * 2560 };
  int* cnt_all = (int*)take(4 * 2560);
  int* cnt4[4] = { cnt_all, cnt_all + 2560, cnt_all + 2 * 2560, cnt_all + 3 * 2560 };
  int* rp_all = (int*)take(4 * 2304);
  int* rp4[4] = { rp_all, rp_all + 2304, rp_all + 2 * 2304, rp_all + 3 * 2304 };
  int* col4[4];
  float* val4[4];
  for (int z = 0; z < 4; z++) {
    col4[z] = (int*)take(m[z]);
    val4[z] = take(m[z]);
  }
  float* Qm = take((size_t)NM * 2048);
  float* Km = take((size_t)NM * 2048);
  float* Vm = take((size_t)NM * 2048);
  float* Qd = take((size_t)ND * 2048);
  float* Kd = take((size_t)ND * 2048);
  float* Vd = take((size_t)ND * 2048);
  float* y_m = take(HN);
  float* y_d = take(HD);

  int pref = 0;
  int epref[5];
  for (int z = 0; z < 4; z++) { epref[z] = pref; pref += m[z]; }
  epref[4] = pref;

  // -------- CSR build (shared by both conv layers) --------
  hipMemsetAsync(dis_all, 0, 4 * 2560 * sizeof(float), stream);
  hipMemsetAsync(cnt_all, 0, 4 * 2560 * sizeof(int), stream);

  DegB db;
  for (int z = 0; z < 4; z++) {
    db.dst[z] = edge[z] + m[z]; db.attr[z] = attr[z];
    db.dis[z] = dis4[z]; db.cnt[z] = cnt4[z];
  }
  for (int z = 0; z < 5; z++) db.epref[z] = epref[z];
  deg_count_b<<<ceil_div(pref, 256), 256, 0, stream>>>(db);

  FinB fn;
  for (int z = 0; z < 4; z++) { fn.dis[z] = dis4[z]; fn.n[z] = nn4[z]; }
  finish_dis_b<<<dim3(ceil_div(ND, 256), 1, 4), 256, 0, stream>>>(fn);

  ScanB sb;
  for (int z = 0; z < 4; z++) { sb.cnt[z] = cnt4[z]; sb.rowptr[z] = rp4[z]; sb.n[z] = nn4[z]; }
  scan_b<<<4, 256, 0, stream>>>(sb);

  hipMemsetAsync(cnt_all, 0, 4 * 2560 * sizeof(int), stream);  // reuse as cursors
  FillB fl;
  for (int z = 0; z < 4; z++) {
    fl.src[z] = edge[z]; fl.dst[z] = edge[z] + m[z]; fl.attr[z] = attr[z];
    fl.rowptr[z] = rp4[z]; fl.cur[z] = cnt4[z]; fl.col[z] = col4[z]; fl.val[z] = val4[z];
  }
  for (int z = 0; z < 5; z++) fl.epref[z] = epref[z];
  fill_b<<<ceil_div(pref, 256), 256, 0, stream>>>(fl);

  // -------- conv1 --------
  BGemm c1;
  const float* xin[4] = { mirna_x, mirna_x, drug_x, drug_x };
  for (int z = 0; z < 4; z++) {
    c1.A[z] = xin[z]; c1.B[z] = (const float*)d_in[10 + 4 * z]; c1.C[z] = h4[z];
    c1.M[z] = nn4[z]; c1.lda[z] = 512;
  }
  for (int z = 4; z < 6; z++) { c1.A[z] = nullptr; c1.B[z] = nullptr; c1.C[z] = nullptr; c1.M[z] = 0; c1.lda[z] = 512; }
  gemm_batched<<<dim3(8, ceil_div(ND, 64), 4), 256, 0, stream>>>(c1);

  float* embp[4] = { emb_m, emb_m + 1024, emb_d, emb_d + 1024 };
  GathB g1;
  for (int z = 0; z < 4; z++) {
    g1.rowptr[z] = rp4[z]; g1.col[z] = col4[z]; g1.val[z] = val4[z];
    g1.dis[z] = dis4[z]; g1.h[z] = h4[z]; g1.b[z] = (const float*)d_in[11 + 4 * z];
    g1.out[z] = embp[z]; g1.n[z] = nn4[z];
  }
  gcn_gather_b<<<dim3(ND, 1, 4), 256, 0, stream>>>(g1);

  // -------- conv2 --------
  BGemm c2 = c1;
  for (int z = 0; z < 4; z++) {
    c2.A[z] = embp[z]; c2.B[z] = (const float*)d_in[12 + 4 * z]; c2.C[z] = h4[z];
    c2.M[z] = nn4[z]; c2.lda[z] = 2048;
  }
  gemm_batched<<<dim3(8, ceil_div(ND, 64), 4), 256, 0, stream>>>(c2);

  GathB g2 = g1;
  for (int z = 0; z < 4; z++) { g2.b[z] = (const float*)d_in[13 + 4 * z]; g2.out[z] = embp[z] + 512; }
  gcn_gather_b<<<dim3(ND, 1, 4), 256, 0, stream>>>(g2);

  // -------- gather to view layout (overwrites h region) --------
  GatherB gt;
  gt.emb[0] = emb_m; gt.emb[1] = emb_d; gt.xv[0] = xv_m; gt.xv[1] = xv_d;
  gt.n[0] = NM; gt.n[1] = ND;
  gather_b<<<dim3(ceil_div(ND * 2048, 256), 1, 2), 256, 0, stream>>>(gt);

  // -------- QKV projections (z=6) --------
  BGemm qkv;
  const float* wq[6] = { (const float*)d_in[26], (const float*)d_in[27], (const float*)d_in[28],
                         (const float*)d_in[32], (const float*)d_in[33], (const float*)d_in[34] };
  float* qkvc[6] = { Qm, Km, Vm, Qd, Kd, Vd };
  for (int z = 0; z < 6; z++) {
    qkv.A[z] = (z < 3) ? xv_m : xv_d; qkv.B[z] = wq[z]; qkv.C[z] = qkvc[z];
    qkv.M[z] = (z < 3) ? 4 * NM : 4 * ND; qkv.lda[z] = 512;
  }
  gemm_batched<<<dim3(8, ceil_div(4 * ND, 64), 6), 256, 0, stream>>>(qkv);

  // -------- attention (o2 -> xv buffers) --------
  AttArgs aa;
  aa.Q[0] = Qm; aa.K[0] = Km; aa.V[0] = Vm; aa.O[0] = xv_m; aa.N[0] = NM;
  aa.Q[1] = Qd; aa.K[1] = Kd; aa.V[1] = Vd; aa.O[1] = xv_d; aa.N[1] = ND;
  attn2_kernel<<<dim3(ceil_div(ND, 32), 32, 2), 256, 0, stream>>>(aa);

  // -------- Wo (mha -> Qm/Qd) --------
  BGemm wo;
  for (int z = 0; z < 2; z++) {
    wo.A[z] = (z == 0) ? xv_m : xv_d;
    wo.B[z] = (const float*)d_in[z == 0 ? 29 : 35];
    wo.C[z] = (z == 0) ? Qm : Qd;
    wo.M[z] = (z == 0) ? 4 * NM : 4 * ND; wo.lda[z] = 512;
  }
  for (int z = 2; z < 6; z++) { wo.A[z] = nullptr; wo.B[z] = nullptr; wo.C[z] = nullptr; wo.M[z] = 0; wo.lda[z] = 512; }
  gemm_batched<<<dim3(8, ceil_div(4 * ND, 64), 2), 256, 0, stream>>>(wo);

  // -------- fuse --------
  FuseB fz;
  fz.mha[0] = Qm; fz.mha[1] = Qd;
  fz.fw[0] = (const float*)d_in[30]; fz.fw[1] = (const float*)d_in[36];
  fz.fb[0] = (const float*)d_in[31]; fz.fb[1] = (const float*)d_in[37];
  fz.y[0] = y_m; fz.y[1] = y_d;
  fz.n[0] = NM; fz.n[1] = ND;
  fuse_b<<<dim3(ceil_div(ND * 512, 256), 1, 2), 256, 0, stream>>>(fz);

  // -------- final: out[i,j] = sum_k y_m[k*NM+i] * y_d[k*ND+j] --------
  gemm_tn<<<dim3(ceil_div(ND, 64), ceil_div(NM, 64)), 256, 0, stream>>>(
      y_m, y_d, out, NM, ND, 512, NM, ND, ND);
}

// Round 6
// 1202.465 us; speedup vs baseline: 8.3308x; 2.1293x over previous
//
#include <hip/hip_runtime.h>
#include <cmath>

#define NM 1043
#define ND 2166

static inline int ceil_div(int a, int b) { return (a + b - 1) / b; }

typedef __attribute__((ext_vector_type(8))) short bf16x8;
typedef __attribute__((ext_vector_type(4))) float f32x4;
typedef __attribute__((ext_vector_type(2))) unsigned int u32x2;
typedef __attribute__((ext_vector_type(4))) unsigned int u32x4;

union U8 { u32x4 u; bf16x8 h; };

__device__ inline unsigned int pkbf(float a, float b) {
  unsigned int ua = __float_as_uint(a), ub = __float_as_uint(b);
  ua += 0x7FFFu + ((ua >> 16) & 1);
  ub += 0x7FFFu + ((ub >> 16) & 1);
  return (ub & 0xFFFF0000u) | (ua >> 16);
}

// ================= batched 64x64x512 GEMM, N=K=ldb=ldc=512 fixed =============
struct BGemm {
  const float* A[6]; const float* B[6]; float* C[6];
  int M[6]; int lda[6];
};

__global__ __launch_bounds__(256) void gemm_batched(BGemm g) {
  const int z = blockIdx.z;
  const int M = g.M[z];
  const int bm = blockIdx.y << 6;
  if (bm >= M) return;
  const int bn = blockIdx.x << 6;
  const int lda = g.lda[z];
  const float* __restrict__ A = g.A[z];
  const float* __restrict__ B = g.B[z];
  float* __restrict__ C = g.C[z];

  __shared__ float As[16][68];
  __shared__ float Bs[16][68];
  const int tid = threadIdx.x;
  const int tx = tid & 15, ty = tid >> 4;
  const int smm = tid >> 2, skq = tid & 3;
  const int skk = tid >> 4, snq = tid & 15;

  float acc[4][4] = {};
  for (int k0 = 0; k0 < 512; k0 += 16) {
    float4 af = make_float4(0.f, 0.f, 0.f, 0.f);
    if (bm + smm < M) af = *(const float4*)&A[(size_t)(bm + smm) * lda + k0 + 4 * skq];
    float4 bf = *(const float4*)&B[(size_t)(k0 + skk) * 512 + bn + 4 * snq];
    __syncthreads();
    As[4 * skq + 0][smm] = af.x;
    As[4 * skq + 1][smm] = af.y;
    As[4 * skq + 2][smm] = af.z;
    As[4 * skq + 3][smm] = af.w;
    *(float4*)&Bs[skk][4 * snq] = bf;
    __syncthreads();
#pragma unroll
    for (int kk = 0; kk < 16; kk++) {
      float4 a4 = *(const float4*)&As[kk][ty * 4];
      float4 b4 = *(const float4*)&Bs[kk][tx * 4];
      acc[0][0] += a4.x * b4.x; acc[0][1] += a4.x * b4.y; acc[0][2] += a4.x * b4.z; acc[0][3] += a4.x * b4.w;
      acc[1][0] += a4.y * b4.x; acc[1][1] += a4.y * b4.y; acc[1][2] += a4.y * b4.z; acc[1][3] += a4.y * b4.w;
      acc[2][0] += a4.z * b4.x; acc[2][1] += a4.z * b4.y; acc[2][2] += a4.z * b4.z; acc[2][3] += a4.z * b4.w;
      acc[3][0] += a4.w * b4.x; acc[3][1] += a4.w * b4.y; acc[3][2] += a4.w * b4.z; acc[3][3] += a4.w * b4.w;
    }
  }
#pragma unroll
  for (int i = 0; i < 4; i++) {
    int row = bm + ty * 4 + i;
    if (row < M) {
      float4 o = make_float4(acc[i][0], acc[i][1], acc[i][2], acc[i][3]);
      *(float4*)&C[(size_t)row * 512 + bn + tx * 4] = o;
    }
  }
}

// ================= final TN GEMM =================
__global__ __launch_bounds__(256) void gemm_tn(
    const float* __restrict__ A, const float* __restrict__ B, float* __restrict__ C,
    int M, int N, int K, int lda, int ldb, int ldc) {
  __shared__ float As[16][65];
  __shared__ float Bs[16][65];
  const int tid = threadIdx.x;
  const int tx = tid & 15, ty = tid >> 4;
  const int bm = blockIdx.y << 6, bn = blockIdx.x << 6;
  float acc[4][4] = {};
  for (int k0 = 0; k0 < K; k0 += 16) {
    for (int i = tid; i < 16 * 64; i += 256) {
      int kk = i >> 6, mm = i & 63;
      int r = k0 + kk, c = bm + mm;
      As[kk][mm] = (r < K && c < M) ? A[(size_t)r * lda + c] : 0.f;
    }
    for (int i = tid; i < 16 * 64; i += 256) {
      int kk = i >> 6, nn = i & 63;
      int r = k0 + kk, c = bn + nn;
      Bs[kk][nn] = (r < K && c < N) ? B[(size_t)r * ldb + c] : 0.f;
    }
    __syncthreads();
#pragma unroll
    for (int kk = 0; kk < 16; kk++) {
      float a[4], b[4];
#pragma unroll
      for (int i = 0; i < 4; i++) a[i] = As[kk][ty + (i << 4)];
#pragma unroll
      for (int j = 0; j < 4; j++) b[j] = Bs[kk][tx + (j << 4)];
#pragma unroll
      for (int i = 0; i < 4; i++)
#pragma unroll
        for (int j = 0; j < 4; j++) acc[i][j] += a[i] * b[j];
    }
    __syncthreads();
  }
#pragma unroll
  for (int i = 0; i < 4; i++) {
    int r = bm + ty + (i << 4);
    if (r >= M) continue;
#pragma unroll
    for (int j = 0; j < 4; j++) {
      int c = bn + tx + (j << 4);
      if (c < N) C[(size_t)r * ldc + c] = acc[i][j];
    }
  }
}

// ================= GCN: CSR build + fused gather =================
struct DegB {
  const int* dst[4]; const float* attr[4];
  float* dis[4]; int* cnt[4];
  int epref[5];
};

__global__ __launch_bounds__(256) void deg_count_b(DegB g) {
  int et = blockIdx.x * 256 + threadIdx.x;
  if (et >= g.epref[4]) return;
  int z = (et >= g.epref[1]) + (et >= g.epref[2]) + (et >= g.epref[3]);
  int e = et - g.epref[z];
  int d = g.dst[z][e];
  atomicAdd(&g.dis[z][d], g.attr[z][e]);
  atomicAdd(&g.cnt[z][d], 1);
}

struct FinB { float* dis[4]; int n[4]; };

__global__ __launch_bounds__(256) void finish_dis_b(FinB g) {
  int z = blockIdx.z;
  int i = blockIdx.x * 256 + threadIdx.x;
  if (i < g.n[z]) g.dis[z][i] = rsqrtf(g.dis[z][i] + 1.0f);
}

struct ScanB { const int* cnt[4]; int* rowptr[4]; int n[4]; };

__global__ __launch_bounds__(256) void scan_b(ScanB s) {
  int z = blockIdx.x;
  int n = s.n[z];
  const int* cnt = s.cnt[z];
  int* rp = s.rowptr[z];
  __shared__ int sums[256];
  int tid = threadIdx.x;
  int chunk = (n + 255) >> 8;
  int start = tid * chunk;
  int local = 0;
  for (int i = 0; i < chunk; i++) {
    int idx = start + i;
    if (idx < n) local += cnt[idx];
  }
  sums[tid] = local;
  __syncthreads();
  for (int off = 1; off < 256; off <<= 1) {
    int t = (tid >= off) ? sums[tid - off] : 0;
    __syncthreads();
    sums[tid] += t;
    __syncthreads();
  }
  int base = sums[tid] - local;
  int total = sums[255];
  int run = base;
  for (int i = 0; i < chunk; i++) {
    int idx = start + i;
    if (idx < n) { rp[idx] = run; run += cnt[idx]; }
  }
  if (tid == 0) rp[n] = total;
}

struct FillB {
  const int* src[4]; const int* dst[4]; const float* attr[4];
  const int* rowptr[4]; int* cur[4]; int* col[4]; float* val[4];
  int epref[5];
};

__global__ __launch_bounds__(256) void fill_b(FillB f) {
  int et = blockIdx.x * 256 + threadIdx.x;
  if (et >= f.epref[4]) return;
  int z = (et >= f.epref[1]) + (et >= f.epref[2]) + (et >= f.epref[3]);
  int e = et - f.epref[z];
  int d = f.dst[z][e];
  int pos = f.rowptr[z][d] + atomicAdd(&f.cur[z][d], 1);
  f.col[z][pos] = f.src[z][e];
  f.val[z][pos] = f.attr[z][e];
}

struct GathB {
  const int* rowptr[4]; const int* col[4]; const float* val[4];
  const float* dis[4]; const float* h[4]; const float* b[4];
  float* out[4]; int n[4];
};

__global__ __launch_bounds__(256) void gcn_gather_b(GathB c) {
  const int z = blockIdx.z;
  const int node = blockIdx.x;
  if (node >= c.n[z]) return;
  const int tid = threadIdx.x;
  const int* __restrict__ col = c.col[z];
  const float* __restrict__ val = c.val[z];
  const float* __restrict__ dis = c.dis[z];
  const float* __restrict__ h = c.h[z];
  const int beg = c.rowptr[z][node], end = c.rowptr[z][node + 1];
  float acc0 = 0.f, acc1 = 0.f;
  int e = beg;
  for (; e + 4 <= end; e += 4) {
    int s0 = col[e], s1 = col[e + 1], s2 = col[e + 2], s3 = col[e + 3];
    float w0 = val[e] * dis[s0];
    float w1 = val[e + 1] * dis[s1];
    float w2 = val[e + 2] * dis[s2];
    float w3 = val[e + 3] * dis[s3];
    const float* p0 = h + ((size_t)s0 << 9);
    const float* p1 = h + ((size_t)s1 << 9);
    const float* p2 = h + ((size_t)s2 << 9);
    const float* p3 = h + ((size_t)s3 << 9);
    acc0 += w0 * p0[tid] + w1 * p1[tid] + w2 * p2[tid] + w3 * p3[tid];
    acc1 += w0 * p0[tid + 256] + w1 * p1[tid + 256] + w2 * p2[tid + 256] + w3 * p3[tid + 256];
  }
  for (; e < end; e++) {
    int s = col[e];
    float w = val[e] * dis[s];
    const float* p = h + ((size_t)s << 9);
    acc0 += w * p[tid];
    acc1 += w * p[tid + 256];
  }
  const float dd = dis[node];
  const float* hp = h + ((size_t)node << 9);
  float o0 = fmaxf(dd * acc0 + dd * dd * hp[tid] + c.b[z][tid], 0.f);
  float o1 = fmaxf(dd * acc1 + dd * dd * hp[tid + 256] + c.b[z][tid + 256], 0.f);
  float* op = c.out[z] + (size_t)node * 2048;
  op[tid] = o0;
  op[tid + 256] = o1;
}

// ================= view gather =================
struct GatherB { const float* emb[2]; float* xv[2]; int n[2]; };

__global__ __launch_bounds__(256) void gather_b(GatherB g) {
  int z = blockIdx.z;
  int n = g.n[z];
  size_t i = (size_t)blockIdx.x * 256 + threadIdx.x;
  if (i >= (size_t)n * 2048) return;
  int e = (int)(i & 511);
  size_t t = i >> 9;
  int v = (int)(t / n);
  int nn = (int)(t - (size_t)v * n);
  g.xv[z][i] = g.emb[z][((size_t)v * 512 + e) * n + nn];
}

// ================= attention v3: MFMA bf16 flash =================
// S^T = K.Q^T per 64-key tile (4 waves x 16 q-rows); softmax in-lane+shfl;
// O^T = V^T.P^T with V transposed in LDS. XOR-swizzled LDS, 16KB total.
struct AttArgs { const float* Q[2]; const float* K[2]; const float* V[2]; float* O[2]; int N[2]; };

__global__ __launch_bounds__(256) void attn3_kernel(AttArgs ar) {
  const int z = blockIdx.z;
  const int N = ar.N[z];
  const int qb = blockIdx.x * 64;
  if (qb >= N) return;
  const int vh = blockIdx.y, v = vh >> 3, h = vh & 7;
  const size_t base = (size_t)v * N * 512 + (size_t)h * 64;
  const float* __restrict__ Qb = ar.Q[z] + base;
  const float* __restrict__ Kb = ar.K[z] + base;
  const float* __restrict__ Vb = ar.V[z] + base;
  float* __restrict__ Ob = ar.O[z] + base;

  __shared__ short kt_s[64 * 64];   // [key][kdim] bf16, swz byte^=(key&7)<<4
  __shared__ short vt_s[64 * 64];   // [d][key]   bf16, swz byte^=(d&15)<<3
  char* ktb = (char*)kt_s;
  char* vtb = (char*)vt_s;

  const int tid = threadIdx.x;
  const int lane = tid & 63;
  const int w = tid >> 6;
  const int a15 = lane & 15;   // q-col / key-subrow / d-subrow
  const int g = lane >> 4;     // k-group
  // staging maps
  const int skr = tid & 63, sg = tid >> 6;       // K: row, col-block
  const int vsr = tid & 15, vsc = tid >> 4;      // V: 4x4 block (key-sub, d-sub)

  // ---- Q fragments (2 kdim steps of 32), scaled by 1/sqrt(64) ----
  const int q = qb + w * 16 + a15;
  bf16x8 qf0, qf1;
  {
    float4 f0 = {}, f1 = {}, f2 = {}, f3 = {};
    if (q < N) {
      const float* qp = Qb + (size_t)q * 512 + g * 8;
      f0 = ((const float4*)qp)[0];
      f1 = ((const float4*)qp)[1];
      f2 = ((const float4*)(qp + 32))[0];
      f3 = ((const float4*)(qp + 32))[1];
    }
    const float s = 0.125f;
    U8 u0, u1;
    u0.u.x = pkbf(f0.x * s, f0.y * s); u0.u.y = pkbf(f0.z * s, f0.w * s);
    u0.u.z = pkbf(f1.x * s, f1.y * s); u0.u.w = pkbf(f1.z * s, f1.w * s);
    u1.u.x = pkbf(f2.x * s, f2.y * s); u1.u.y = pkbf(f2.z * s, f2.w * s);
    u1.u.z = pkbf(f3.x * s, f3.y * s); u1.u.w = pkbf(f3.z * s, f3.w * s);
    qf0 = u0.h; qf1 = u1.h;
  }

  float rm = -INFINITY, rs = 0.f;
  f32x4 o0 = {0.f, 0.f, 0.f, 0.f}, o1 = o0, o2 = o0, o3 = o0;

  const int swzk = (a15 & 7) << 4;
  const int swzv = a15 << 3;

  for (int kb = 0; kb < N; kb += 64) {
    __syncthreads();
    // ---- stage K tile (row-major bf16, swizzled) ----
    {
      const int row = kb + skr;
      float4 a = {}, b = {}, c = {}, d = {};
      if (row < N) {
        const float* kp = Kb + (size_t)row * 512 + sg * 16;
        a = ((const float4*)kp)[0]; b = ((const float4*)kp)[1];
        c = ((const float4*)kp)[2]; d = ((const float4*)kp)[3];
      }
      const int sw = (skr & 7) << 4;
      u32x4 wk;
      wk.x = pkbf(a.x, a.y); wk.y = pkbf(a.z, a.w);
      wk.z = pkbf(b.x, b.y); wk.w = pkbf(b.z, b.w);
      *(u32x4*)(ktb + skr * 128 + ((sg * 32) ^ sw)) = wk;
      wk.x = pkbf(c.x, c.y); wk.y = pkbf(c.z, c.w);
      wk.z = pkbf(d.x, d.y); wk.w = pkbf(d.z, d.w);
      *(u32x4*)(ktb + skr * 128 + ((sg * 32 + 16) ^ sw)) = wk;
    }
    // ---- stage V tile transposed (d-major, swizzled) ----
    {
      const int r0 = kb + 4 * vsr;
      float4 f0 = {}, f1 = {}, f2 = {}, f3 = {};
      const float* vp = Vb + (size_t)r0 * 512 + 4 * vsc;
      if (r0 + 0 < N) f0 = *(const float4*)(vp);
      if (r0 + 1 < N) f1 = *(const float4*)(vp + 512);
      if (r0 + 2 < N) f2 = *(const float4*)(vp + 1024);
      if (r0 + 3 < N) f3 = *(const float4*)(vp + 1536);
      const int dd = 4 * vsc;
      const int kby = 8 * vsr;
      u32x2 wv;
      wv.x = pkbf(f0.x, f1.x); wv.y = pkbf(f2.x, f3.x);
      *(u32x2*)(vtb + (dd + 0) * 128 + (kby ^ (((dd + 0) & 15) << 3))) = wv;
      wv.x = pkbf(f0.y, f1.y); wv.y = pkbf(f2.y, f3.y);
      *(u32x2*)(vtb + (dd + 1) * 128 + (kby ^ (((dd + 1) & 15) << 3))) = wv;
      wv.x = pkbf(f0.z, f1.z); wv.y = pkbf(f2.z, f3.z);
      *(u32x2*)(vtb + (dd + 2) * 128 + (kby ^ (((dd + 2) & 15) << 3))) = wv;
      wv.x = pkbf(f0.w, f1.w); wv.y = pkbf(f2.w, f3.w);
      *(u32x2*)(vtb + (dd + 3) * 128 + (kby ^ (((dd + 3) & 15) << 3))) = wv;
    }
    __syncthreads();

    // ---- QK^T: sf[m] = S^T subtiles (key = kb+16m+4g+reg, qcol = a15) ----
    f32x4 sf0 = {0.f, 0.f, 0.f, 0.f}, sf1 = sf0, sf2 = sf0, sf3 = sf0;
#define QK(m, sfm, s2, qfr) \
    sfm = __builtin_amdgcn_mfma_f32_16x16x32_bf16( \
        *(const bf16x8*)(ktb + (16 * m + a15) * 128 + ((64 * s2 + 16 * g) ^ swzk)), \
        qfr, sfm, 0, 0, 0);
    QK(0, sf0, 0, qf0) QK(1, sf1, 0, qf0) QK(2, sf2, 0, qf0) QK(3, sf3, 0, qf0)
    QK(0, sf0, 1, qf1) QK(1, sf1, 1, qf1) QK(2, sf2, 1, qf1) QK(3, sf3, 1, qf1)
#undef QK

    // ---- mask tail keys ----
    if (kb + 64 > N) {
#define MSK(sfm, m) { int kk = kb + 16 * m + 4 * g; \
      if (kk + 0 >= N) sfm.x = -INFINITY; \
      if (kk + 1 >= N) sfm.y = -INFINITY; \
      if (kk + 2 >= N) sfm.z = -INFINITY; \
      if (kk + 3 >= N) sfm.w = -INFINITY; }
      MSK(sf0, 0) MSK(sf1, 1) MSK(sf2, 2) MSK(sf3, 3)
#undef MSK
    }

    // ---- online softmax (per-lane q = a15; reduce over keys via lhi shfl) ----
    float tmax = fmaxf(fmaxf(fmaxf(sf0.x, sf0.y), fmaxf(sf0.z, sf0.w)),
                       fmaxf(fmaxf(sf1.x, sf1.y), fmaxf(sf1.z, sf1.w)));
    tmax = fmaxf(tmax, fmaxf(fmaxf(fmaxf(sf2.x, sf2.y), fmaxf(sf2.z, sf2.w)),
                             fmaxf(fmaxf(sf3.x, sf3.y), fmaxf(sf3.z, sf3.w))));
    tmax = fmaxf(tmax, __shfl_xor(tmax, 16));
    tmax = fmaxf(tmax, __shfl_xor(tmax, 32));
    const float nm = fmaxf(rm, tmax);
    const float sc = __expf(rm - nm);
    float ps = 0.f;
    u32x4 pr0, pr1, pr2, pr3;
#define SMX(sfm, prm) { float e; unsigned int u; \
    e = __expf(sfm.x - nm); u = __float_as_uint(e); u += 0x7FFFu + ((u >> 16) & 1); u &= 0xFFFF0000u; ps += __uint_as_float(u); prm.x = u; \
    e = __expf(sfm.y - nm); u = __float_as_uint(e); u += 0x7FFFu + ((u >> 16) & 1); u &= 0xFFFF0000u; ps += __uint_as_float(u); prm.y = u; \
    e = __expf(sfm.z - nm); u = __float_as_uint(e); u += 0x7FFFu + ((u >> 16) & 1); u &= 0xFFFF0000u; ps += __uint_as_float(u); prm.z = u; \
    e = __expf(sfm.w - nm); u = __float_as_uint(e); u += 0x7FFFu + ((u >> 16) & 1); u &= 0xFFFF0000u; ps += __uint_as_float(u); prm.w = u; }
    SMX(sf0, pr0) SMX(sf1, pr1) SMX(sf2, pr2) SMX(sf3, pr3)
#undef SMX
    ps += __shfl_xor(ps, 16);
    ps += __shfl_xor(ps, 32);
    rs = rs * sc + ps;
    rm = nm;
    o0 *= sc; o1 *= sc; o2 *= sc; o3 *= sc;

    // ---- PV: O^T += V^T . P^T ----
    U8 pb0, pb1;
    pb0.u.x = (pr0.x >> 16) | pr0.y;  pb0.u.y = (pr0.z >> 16) | pr0.w;
    pb0.u.z = (pr1.x >> 16) | pr1.y;  pb0.u.w = (pr1.z >> 16) | pr1.w;
    pb1.u.x = (pr2.x >> 16) | pr2.y;  pb1.u.y = (pr2.z >> 16) | pr2.w;
    pb1.u.z = (pr3.x >> 16) | pr3.y;  pb1.u.w = (pr3.z >> 16) | pr3.w;
#define PV(md, om, s2, pbr) { \
    const char* vr = vtb + (16 * md + a15) * 128; \
    u32x2 v0 = *(const u32x2*)(vr + ((64 * s2 + 8 * g) ^ swzv)); \
    u32x2 v1 = *(const u32x2*)(vr + ((64 * s2 + 32 + 8 * g) ^ swzv)); \
    U8 av; av.u.x = v0.x; av.u.y = v0.y; av.u.z = v1.x; av.u.w = v1.y; \
    om = __builtin_amdgcn_mfma_f32_16x16x32_bf16(av.h, pbr, om, 0, 0, 0); }
    PV(0, o0, 0, pb0.h) PV(1, o1, 0, pb0.h) PV(2, o2, 0, pb0.h) PV(3, o3, 0, pb0.h)
    PV(0, o0, 1, pb1.h) PV(1, o1, 1, pb1.h) PV(2, o2, 1, pb1.h) PV(3, o3, 1, pb1.h)
#undef PV
  }

  // ---- store O (row q, d = 16*md + 4g + reg) ----
  if (q < N) {
    const float inv = 1.0f / rs;
    float* op = Ob + (size_t)q * 512 + 4 * g;
    float4 r;
    r.x = o0.x * inv; r.y = o0.y * inv; r.z = o0.z * inv; r.w = o0.w * inv;
    *(float4*)(op + 0) = r;
    r.x = o1.x * inv; r.y = o1.y * inv; r.z = o1.z * inv; r.w = o1.w * inv;
    *(float4*)(op + 16) = r;
    r.x = o2.x * inv; r.y = o2.y * inv; r.z = o2.z * inv; r.w = o2.w * inv;
    *(float4*)(op + 32) = r;
    r.x = o3.x * inv; r.y = o3.y * inv; r.z = o3.z * inv; r.w = o3.w * inv;
    *(float4*)(op + 48) = r;
  }
}

// ================= fuse =================
struct FuseB { const float* mha[2]; const float* fw[2]; const float* fb[2]; float* y[2]; int n[2]; };

__global__ __launch_bounds__(256) void fuse_b(FuseB fz) {
  int z = blockIdx.z;
  int n = fz.n[z];
  int i = blockIdx.x * 256 + threadIdx.x;
  if (i >= n * 512) return;
  size_t stride = (size_t)n * 512;
  const float* m = fz.mha[z];
  const float* fw = fz.fw[z];
  float acc = fz.fb[z][0];
  acc += fw[0] * m[i];
  acc += fw[1] * m[stride + i];
  acc += fw[2] * m[2 * stride + i];
  acc += fw[3] * m[3 * stride + i];
  fz.y[z][i] = acc;
}

// ================= launch =================
extern "C" void kernel_launch(void* const* d_in, const int* in_sizes, int n_in,
                              void* d_out, int out_size, void* d_ws, size_t ws_size,
                              hipStream_t stream) {
  const float* mirna_x = (const float*)d_in[0];
  const float* drug_x  = (const float*)d_in[1];
  const int* edge[4] = { (const int*)d_in[2], (const int*)d_in[4], (const int*)d_in[6], (const int*)d_in[8] };
  const float* attr[4] = { (const float*)d_in[3], (const float*)d_in[5], (const float*)d_in[7], (const float*)d_in[9] };
  const int m[4] = { in_sizes[2] / 2, in_sizes[4] / 2, in_sizes[6] / 2, in_sizes[8] / 2 };
  const int nn4[4] = { NM, NM, ND, ND };
  float* out = (float*)d_out;

  float* ws = (float*)d_ws;
  size_t off = 0;
  auto take = [&](size_t nelem) {
    float* r = ws + off;
    off += (nelem + 255) & ~(size_t)255;
    return r;
  };
  const size_t HN = (size_t)NM * 512, HD = (size_t)ND * 512;
  const size_t HALL = 2 * HN + 2 * HD;
  float* emb_m = take((size_t)NM * 2048);
  float* emb_d = take((size_t)ND * 2048);
  float* region = take(2 * HALL);
  float* h4[4] = { region, region + HN, region + 2 * HN, region + 2 * HN + HD };
  float* xv_m = region;
  float* xv_d = region + (size_t)NM * 2048;
  float* dis_all = take(4 * 2560);
  float* dis4[4] = { dis_all, dis_all + 2560, dis_all + 2 * 2560, dis_all + 3 * 2560 };
  int* cnt_all = (int*)take(4 * 2560);
  int* cnt4[4] = { cnt_all, cnt_all + 2560, cnt_all + 2 * 2560, cnt_all + 3 * 2560 };
  int* rp_all = (int*)take(4 * 2304);
  int* rp4[4] = { rp_all, rp_all + 2304, rp_all + 2 * 2304, rp_all + 3 * 2304 };
  int* col4[4];
  float* val4[4];
  for (int z = 0; z < 4; z++) {
    col4[z] = (int*)take(m[z]);
    val4[z] = take(m[z]);
  }
  float* Qm = take((size_t)NM * 2048);
  float* Km = take((size_t)NM * 2048);
  float* Vm = take((size_t)NM * 2048);
  float* Qd = take((size_t)ND * 2048);
  float* Kd = take((size_t)ND * 2048);
  float* Vd = take((size_t)ND * 2048);
  float* y_m = take(HN);
  float* y_d = take(HD);

  int pref = 0;
  int epref[5];
  for (int z = 0; z < 4; z++) { epref[z] = pref; pref += m[z]; }
  epref[4] = pref;

  // -------- CSR build --------
  hipMemsetAsync(dis_all, 0, 4 * 2560 * sizeof(float), stream);
  hipMemsetAsync(cnt_all, 0, 4 * 2560 * sizeof(int), stream);

  DegB db;
  for (int z = 0; z < 4; z++) {
    db.dst[z] = edge[z] + m[z]; db.attr[z] = attr[z];
    db.dis[z] = dis4[z]; db.cnt[z] = cnt4[z];
  }
  for (int z = 0; z < 5; z++) db.epref[z] = epref[z];
  deg_count_b<<<ceil_div(pref, 256), 256, 0, stream>>>(db);

  FinB fn;
  for (int z = 0; z < 4; z++) { fn.dis[z] = dis4[z]; fn.n[z] = nn4[z]; }
  finish_dis_b<<<dim3(ceil_div(ND, 256), 1, 4), 256, 0, stream>>>(fn);

  ScanB sb;
  for (int z = 0; z < 4; z++) { sb.cnt[z] = cnt4[z]; sb.rowptr[z] = rp4[z]; sb.n[z] = nn4[z]; }
  scan_b<<<4, 256, 0, stream>>>(sb);

  hipMemsetAsync(cnt_all, 0, 4 * 2560 * sizeof(int), stream);
  FillB fl;
  for (int z = 0; z < 4; z++) {
    fl.src[z] = edge[z]; fl.dst[z] = edge[z] + m[z]; fl.attr[z] = attr[z];
    fl.rowptr[z] = rp4[z]; fl.cur[z] = cnt4[z]; fl.col[z] = col4[z]; fl.val[z] = val4[z];
  }
  for (int z = 0; z < 5; z++) fl.epref[z] = epref[z];
  fill_b<<<ceil_div(pref, 256), 256, 0, stream>>>(fl);

  // -------- conv1 --------
  BGemm c1;
  const float* xin[4] = { mirna_x, mirna_x, drug_x, drug_x };
  for (int z = 0; z < 4; z++) {
    c1.A[z] = xin[z]; c1.B[z] = (const float*)d_in[10 + 4 * z]; c1.C[z] = h4[z];
    c1.M[z] = nn4[z]; c1.lda[z] = 512;
  }
  for (int z = 4; z < 6; z++) { c1.A[z] = nullptr; c1.B[z] = nullptr; c1.C[z] = nullptr; c1.M[z] = 0; c1.lda[z] = 512; }
  gemm_batched<<<dim3(8, ceil_div(ND, 64), 4), 256, 0, stream>>>(c1);

  float* embp[4] = { emb_m, emb_m + 1024, emb_d, emb_d + 1024 };
  GathB g1;
  for (int z = 0; z < 4; z++) {
    g1.rowptr[z] = rp4[z]; g1.col[z] = col4[z]; g1.val[z] = val4[z];
    g1.dis[z] = dis4[z]; g1.h[z] = h4[z]; g1.b[z] = (const float*)d_in[11 + 4 * z];
    g1.out[z] = embp[z]; g1.n[z] = nn4[z];
  }
  gcn_gather_b<<<dim3(ND, 1, 4), 256, 0, stream>>>(g1);

  // -------- conv2 --------
  BGemm c2 = c1;
  for (int z = 0; z < 4; z++) {
    c2.A[z] = embp[z]; c2.B[z] = (const float*)d_in[12 + 4 * z]; c2.C[z] = h4[z];
    c2.M[z] = nn4[z]; c2.lda[z] = 2048;
  }
  gemm_batched<<<dim3(8, ceil_div(ND, 64), 4), 256, 0, stream>>>(c2);

  GathB g2 = g1;
  for (int z = 0; z < 4; z++) { g2.b[z] = (const float*)d_in[13 + 4 * z]; g2.out[z] = embp[z] + 512; }
  gcn_gather_b<<<dim3(ND, 1, 4), 256, 0, stream>>>(g2);

  // -------- gather to view layout --------
  GatherB gt;
  gt.emb[0] = emb_m; gt.emb[1] = emb_d; gt.xv[0] = xv_m; gt.xv[1] = xv_d;
  gt.n[0] = NM; gt.n[1] = ND;
  gather_b<<<dim3(ceil_div(ND * 2048, 256), 1, 2), 256, 0, stream>>>(gt);

  // -------- QKV projections --------
  BGemm qkv;
  const float* wq[6] = { (const float*)d_in[26], (const float*)d_in[27], (const float*)d_in[28],
                         (const float*)d_in[32], (const float*)d_in[33], (const float*)d_in[34] };
  float* qkvc[6] = { Qm, Km, Vm, Qd, Kd, Vd };
  for (int z = 0; z < 6; z++) {
    qkv.A[z] = (z < 3) ? xv_m : xv_d; qkv.B[z] = wq[z]; qkv.C[z] = qkvc[z];
    qkv.M[z] = (z < 3) ? 4 * NM : 4 * ND; qkv.lda[z] = 512;
  }
  gemm_batched<<<dim3(8, ceil_div(4 * ND, 64), 6), 256, 0, stream>>>(qkv);

  // -------- attention (MFMA, o2 -> xv buffers) --------
  AttArgs aa;
  aa.Q[0] = Qm; aa.K[0] = Km; aa.V[0] = Vm; aa.O[0] = xv_m; aa.N[0] = NM;
  aa.Q[1] = Qd; aa.K[1] = Kd; aa.V[1] = Vd; aa.O[1] = xv_d; aa.N[1] = ND;
  attn3_kernel<<<dim3(ceil_div(ND, 64), 32, 2), 256, 0, stream>>>(aa);

  // -------- Wo --------
  BGemm wo;
  for (int z = 0; z < 2; z++) {
    wo.A[z] = (z == 0) ? xv_m : xv_d;
    wo.B[z] = (const float*)d_in[z == 0 ? 29 : 35];
    wo.C[z] = (z == 0) ? Qm : Qd;
    wo.M[z] = (z == 0) ? 4 * NM : 4 * ND; wo.lda[z] = 512;
  }
  for (int z = 2; z < 6; z++) { wo.A[z] = nullptr; wo.B[z] = nullptr; wo.C[z] = nullptr; wo.M[z] = 0; wo.lda[z] = 512; }
  gemm_batched<<<dim3(8, ceil_div(4 * ND, 64), 2), 256, 0, stream>>>(wo);

  // -------- fuse --------
  FuseB fz;
  fz.mha[0] = Qm; fz.mha[1] = Qd;
  fz.fw[0] = (const float*)d_in[30]; fz.fw[1] = (const float*)d_in[36];
  fz.fb[0] = (const float*)d_in[31]; fz.fb[1] = (const float*)d_in[37];
  fz.y[0] = y_m; fz.y[1] = y_d;
  fz.n[0] = NM; fz.n[1] = ND;
  fuse_b<<<dim3(ceil_div(ND * 512, 256), 1, 2), 256, 0, stream>>>(fz);

  // -------- final TN GEMM --------
  gemm_tn<<<dim3(ceil_div(ND, 64), ceil_div(NM, 64)), 256, 0, stream>>>(
      y_m, y_d, out, NM, ND, 512, NM, ND, ND);
}

// Round 7
// 866.481 us; speedup vs baseline: 11.5611x; 1.3878x over previous
//
#include <hip/hip_runtime.h>
#include <cmath>

#define NM 1043
#define ND 2166

static inline int ceil_div(int a, int b) { return (a + b - 1) / b; }

typedef __attribute__((ext_vector_type(8))) short bf16x8;
typedef __attribute__((ext_vector_type(4))) float f32x4;
typedef __attribute__((ext_vector_type(2))) unsigned int u32x2;
typedef __attribute__((ext_vector_type(4))) unsigned int u32x4;

union U8 { u32x4 u; bf16x8 h; };

__device__ inline unsigned int pkbf(float a, float b) {
  unsigned int ua = __float_as_uint(a), ub = __float_as_uint(b);
  ua += 0x7FFFu + ((ua >> 16) & 1);
  ub += 0x7FFFu + ((ub >> 16) & 1);
  return (ub & 0xFFFF0000u) | (ua >> 16);
}

__device__ inline unsigned short bf1(float a) {
  unsigned int ua = __float_as_uint(a);
  ua += 0x7FFFu + ((ua >> 16) & 1);
  return (unsigned short)(ua >> 16);
}

// ============ weight prep: W[k][n] f32 -> Wt[n][k] bf16 (16 matrices) ========
struct PrepW { const float* W[16]; unsigned short* Wt[16]; };

__global__ __launch_bounds__(256) void prep_w(PrepW p) {
  const int z = blockIdx.z;
  const float* __restrict__ W = p.W[z];
  unsigned short* __restrict__ Wt = p.Wt[z];
  const int n0 = blockIdx.x * 64, k0 = blockIdx.y * 64;
  __shared__ float Ws[64][65];
  const int tid = threadIdx.x;
#pragma unroll
  for (int it = 0; it < 16; it++) {
    int i = it * 256 + tid;
    int k = i >> 6, n = i & 63;
    Ws[k][n] = W[(size_t)(k0 + k) * 512 + n0 + n];
  }
  __syncthreads();
#pragma unroll
  for (int it = 0; it < 16; it++) {
    int i = it * 256 + tid;
    int n = i >> 6, k = i & 63;
    Wt[(size_t)(n0 + n) * 512 + k0 + k] = bf1(Ws[k][n]);
  }
}

// ============ batched MFMA GEMM: C[M,512] = A[M,512] @ W, Bt = W^T bf16 ======
struct BGemm {
  const float* A[6]; const unsigned short* Bt[6]; float* C[6];
  int M[6]; int lda[6];
};

__global__ __launch_bounds__(256) void gemm_mfma(BGemm g) {
  const int z = blockIdx.z;
  const int M = g.M[z];
  const int bm = blockIdx.y << 7;
  if (bm >= M) return;
  const int bn = blockIdx.x << 7;
  const int lda = g.lda[z];
  const float* __restrict__ A = g.A[z];
  const char* __restrict__ Btб = (const char*)g.Bt[z];
  float* __restrict__ C = g.C[z];

  __shared__ short As_s[128 * 64];
  __shared__ short Bs_s[128 * 64];
  char* asb = (char*)As_s;
  char* bsb = (char*)Bs_s;

  const int tid = threadIdx.x;
  const int lane = tid & 63;
  const int w = tid >> 6;
  const int wm = (w >> 1) << 6, wn = (w & 1) << 6;
  const int fr = lane & 15, kg = lane >> 4;

  f32x4 acc[4][4];
#pragma unroll
  for (int i = 0; i < 4; i++)
#pragma unroll
    for (int j = 0; j < 4; j++) acc[i][j] = (f32x4){0.f, 0.f, 0.f, 0.f};

  for (int kb = 0; kb < 512; kb += 64) {
    __syncthreads();  // prior-iter readers done
    // ---- stage A tile 128x64 f32->bf16, swizzled ----
#pragma unroll
    for (int qi = 0; qi < 4; qi++) {
      int qid = qi * 256 + tid;
      int mm = qid >> 3, qk = qid & 7;
      float4 f0 = {}, f1 = {};
      if (bm + mm < M) {
        const float* ap = A + (size_t)(bm + mm) * lda + kb + qk * 8;
        f0 = ((const float4*)ap)[0];
        f1 = ((const float4*)ap)[1];
      }
      u32x4 wv;
      wv.x = pkbf(f0.x, f0.y); wv.y = pkbf(f0.z, f0.w);
      wv.z = pkbf(f1.x, f1.y); wv.w = pkbf(f1.z, f1.w);
      *(u32x4*)(asb + mm * 128 + ((qk * 16) ^ ((mm & 7) << 4))) = wv;
    }
    // ---- stage Bt tile 128x64 bf16 (already bf16 in global), swizzled ----
#pragma unroll
    for (int qi = 0; qi < 4; qi++) {
      int qid = qi * 256 + tid;
      int nn = qid >> 3, qk = qid & 7;
      u32x4 bv = *(const u32x4*)(Btб + (((size_t)(bn + nn)) << 10) + (kb + qk * 8) * 2);
      *(u32x4*)(bsb + nn * 128 + ((qk * 16) ^ ((nn & 7) << 4))) = bv;
    }
    __syncthreads();

#pragma unroll
    for (int ks = 0; ks < 2; ks++) {
      bf16x8 af[4], bfv[4];
#pragma unroll
      for (int i = 0; i < 4; i++) {
        int row = wm + i * 16 + fr;
        af[i] = *(const bf16x8*)(asb + row * 128 + (((ks * 64) + kg * 16) ^ ((row & 7) << 4)));
      }
#pragma unroll
      for (int j = 0; j < 4; j++) {
        int row = wn + j * 16 + fr;
        bfv[j] = *(const bf16x8*)(bsb + row * 128 + (((ks * 64) + kg * 16) ^ ((row & 7) << 4)));
      }
#pragma unroll
      for (int i = 0; i < 4; i++)
#pragma unroll
        for (int j = 0; j < 4; j++)
          acc[i][j] = __builtin_amdgcn_mfma_f32_16x16x32_bf16(af[i], bfv[j], acc[i][j], 0, 0, 0);
    }
  }

  // ---- epilogue: row = bm+wm+i*16+kg*4+r, col = bn+wn+j*16+fr ----
#pragma unroll
  for (int i = 0; i < 4; i++) {
    int m0 = bm + wm + i * 16 + kg * 4;
#pragma unroll
    for (int j = 0; j < 4; j++) {
      int n = bn + wn + j * 16 + fr;
#pragma unroll
      for (int r = 0; r < 4; r++) {
        if (m0 + r < M) C[(size_t)(m0 + r) * 512 + n] = acc[i][j][r];
      }
    }
  }
}

// ================= final TN GEMM (f32, unchanged) =================
__global__ __launch_bounds__(256) void gemm_tn(
    const float* __restrict__ A, const float* __restrict__ B, float* __restrict__ C,
    int M, int N, int K, int lda, int ldb, int ldc) {
  __shared__ float As[16][65];
  __shared__ float Bs[16][65];
  const int tid = threadIdx.x;
  const int tx = tid & 15, ty = tid >> 4;
  const int bm = blockIdx.y << 6, bn = blockIdx.x << 6;
  float acc[4][4] = {};
  for (int k0 = 0; k0 < K; k0 += 16) {
    for (int i = tid; i < 16 * 64; i += 256) {
      int kk = i >> 6, mm = i & 63;
      int r = k0 + kk, c = bm + mm;
      As[kk][mm] = (r < K && c < M) ? A[(size_t)r * lda + c] : 0.f;
    }
    for (int i = tid; i < 16 * 64; i += 256) {
      int kk = i >> 6, nn = i & 63;
      int r = k0 + kk, c = bn + nn;
      Bs[kk][nn] = (r < K && c < N) ? B[(size_t)r * ldb + c] : 0.f;
    }
    __syncthreads();
#pragma unroll
    for (int kk = 0; kk < 16; kk++) {
      float a[4], b[4];
#pragma unroll
      for (int i = 0; i < 4; i++) a[i] = As[kk][ty + (i << 4)];
#pragma unroll
      for (int j = 0; j < 4; j++) b[j] = Bs[kk][tx + (j << 4)];
#pragma unroll
      for (int i = 0; i < 4; i++)
#pragma unroll
        for (int j = 0; j < 4; j++) acc[i][j] += a[i] * b[j];
    }
    __syncthreads();
  }
#pragma unroll
  for (int i = 0; i < 4; i++) {
    int r = bm + ty + (i << 4);
    if (r >= M) continue;
#pragma unroll
    for (int j = 0; j < 4; j++) {
      int c = bn + tx + (j << 4);
      if (c < N) C[(size_t)r * ldc + c] = acc[i][j];
    }
  }
}

// ================= GCN: CSR build + fused gather =================
struct DegB {
  const int* dst[4]; const float* attr[4];
  float* dis[4]; int* cnt[4];
  int epref[5];
};

__global__ __launch_bounds__(256) void deg_count_b(DegB g) {
  int et = blockIdx.x * 256 + threadIdx.x;
  if (et >= g.epref[4]) return;
  int z = (et >= g.epref[1]) + (et >= g.epref[2]) + (et >= g.epref[3]);
  int e = et - g.epref[z];
  int d = g.dst[z][e];
  atomicAdd(&g.dis[z][d], g.attr[z][e]);
  atomicAdd(&g.cnt[z][d], 1);
}

struct FinB { float* dis[4]; int n[4]; };

__global__ __launch_bounds__(256) void finish_dis_b(FinB g) {
  int z = blockIdx.z;
  int i = blockIdx.x * 256 + threadIdx.x;
  if (i < g.n[z]) g.dis[z][i] = rsqrtf(g.dis[z][i] + 1.0f);
}

struct ScanB { const int* cnt[4]; int* rowptr[4]; int n[4]; };

__global__ __launch_bounds__(256) void scan_b(ScanB s) {
  int z = blockIdx.x;
  int n = s.n[z];
  const int* cnt = s.cnt[z];
  int* rp = s.rowptr[z];
  __shared__ int sums[256];
  int tid = threadIdx.x;
  int chunk = (n + 255) >> 8;
  int start = tid * chunk;
  int local = 0;
  for (int i = 0; i < chunk; i++) {
    int idx = start + i;
    if (idx < n) local += cnt[idx];
  }
  sums[tid] = local;
  __syncthreads();
  for (int off = 1; off < 256; off <<= 1) {
    int t = (tid >= off) ? sums[tid - off] : 0;
    __syncthreads();
    sums[tid] += t;
    __syncthreads();
  }
  int base = sums[tid] - local;
  int total = sums[255];
  int run = base;
  for (int i = 0; i < chunk; i++) {
    int idx = start + i;
    if (idx < n) { rp[idx] = run; run += cnt[idx]; }
  }
  if (tid == 0) rp[n] = total;
}

struct FillB {
  const int* src[4]; const int* dst[4]; const float* attr[4];
  const int* rowptr[4]; int* cur[4]; int* col[4]; float* val[4];
  int epref[5];
};

__global__ __launch_bounds__(256) void fill_b(FillB f) {
  int et = blockIdx.x * 256 + threadIdx.x;
  if (et >= f.epref[4]) return;
  int z = (et >= f.epref[1]) + (et >= f.epref[2]) + (et >= f.epref[3]);
  int e = et - f.epref[z];
  int d = f.dst[z][e];
  int pos = f.rowptr[z][d] + atomicAdd(&f.cur[z][d], 1);
  f.col[z][pos] = f.src[z][e];
  f.val[z][pos] = f.attr[z][e];
}

struct GathB {
  const int* rowptr[4]; const int* col[4]; const float* val[4];
  const float* dis[4]; const float* h[4]; const float* b[4];
  float* out[4]; int n[4];
};

__global__ __launch_bounds__(256) void gcn_gather_b(GathB c) {
  const int z = blockIdx.z;
  const int node = blockIdx.x;
  if (node >= c.n[z]) return;
  const int tid = threadIdx.x;
  const int* __restrict__ col = c.col[z];
  const float* __restrict__ val = c.val[z];
  const float* __restrict__ dis = c.dis[z];
  const float* __restrict__ h = c.h[z];
  const int beg = c.rowptr[z][node], end = c.rowptr[z][node + 1];
  float acc0 = 0.f, acc1 = 0.f;
  int e = beg;
  for (; e + 4 <= end; e += 4) {
    int s0 = col[e], s1 = col[e + 1], s2 = col[e + 2], s3 = col[e + 3];
    float w0 = val[e] * dis[s0];
    float w1 = val[e + 1] * dis[s1];
    float w2 = val[e + 2] * dis[s2];
    float w3 = val[e + 3] * dis[s3];
    const float* p0 = h + ((size_t)s0 << 9);
    const float* p1 = h + ((size_t)s1 << 9);
    const float* p2 = h + ((size_t)s2 << 9);
    const float* p3 = h + ((size_t)s3 << 9);
    acc0 += w0 * p0[tid] + w1 * p1[tid] + w2 * p2[tid] + w3 * p3[tid];
    acc1 += w0 * p0[tid + 256] + w1 * p1[tid + 256] + w2 * p2[tid + 256] + w3 * p3[tid + 256];
  }
  for (; e < end; e++) {
    int s = col[e];
    float w = val[e] * dis[s];
    const float* p = h + ((size_t)s << 9);
    acc0 += w * p[tid];
    acc1 += w * p[tid + 256];
  }
  const float dd = dis[node];
  const float* hp = h + ((size_t)node << 9);
  float o0 = fmaxf(dd * acc0 + dd * dd * hp[tid] + c.b[z][tid], 0.f);
  float o1 = fmaxf(dd * acc1 + dd * dd * hp[tid + 256] + c.b[z][tid + 256], 0.f);
  float* op = c.out[z] + (size_t)node * 2048;
  op[tid] = o0;
  op[tid + 256] = o1;
}

// ================= view gather =================
struct GatherB { const float* emb[2]; float* xv[2]; int n[2]; };

__global__ __launch_bounds__(256) void gather_b(GatherB g) {
  int z = blockIdx.z;
  int n = g.n[z];
  size_t i = (size_t)blockIdx.x * 256 + threadIdx.x;
  if (i >= (size_t)n * 2048) return;
  int e = (int)(i & 511);
  size_t t = i >> 9;
  int v = (int)(t / n);
  int nn = (int)(t - (size_t)v * n);
  g.xv[z][i] = g.emb[z][((size_t)v * 512 + e) * n + nn];
}

// ================= attention v3: MFMA bf16 flash (unchanged) =================
struct AttArgs { const float* Q[2]; const float* K[2]; const float* V[2]; float* O[2]; int N[2]; };

__global__ __launch_bounds__(256) void attn3_kernel(AttArgs ar) {
  const int z = blockIdx.z;
  const int N = ar.N[z];
  const int qb = blockIdx.x * 64;
  if (qb >= N) return;
  const int vh = blockIdx.y, v = vh >> 3, h = vh & 7;
  const size_t base = (size_t)v * N * 512 + (size_t)h * 64;
  const float* __restrict__ Qb = ar.Q[z] + base;
  const float* __restrict__ Kb = ar.K[z] + base;
  const float* __restrict__ Vb = ar.V[z] + base;
  float* __restrict__ Ob = ar.O[z] + base;

  __shared__ short kt_s[64 * 64];
  __shared__ short vt_s[64 * 64];
  char* ktb = (char*)kt_s;
  char* vtb = (char*)vt_s;

  const int tid = threadIdx.x;
  const int lane = tid & 63;
  const int w = tid >> 6;
  const int a15 = lane & 15;
  const int g = lane >> 4;
  const int skr = tid & 63, sg = tid >> 6;
  const int vsr = tid & 15, vsc = tid >> 4;

  const int q = qb + w * 16 + a15;
  bf16x8 qf0, qf1;
  {
    float4 f0 = {}, f1 = {}, f2 = {}, f3 = {};
    if (q < N) {
      const float* qp = Qb + (size_t)q * 512 + g * 8;
      f0 = ((const float4*)qp)[0];
      f1 = ((const float4*)qp)[1];
      f2 = ((const float4*)(qp + 32))[0];
      f3 = ((const float4*)(qp + 32))[1];
    }
    const float s = 0.125f;
    U8 u0, u1;
    u0.u.x = pkbf(f0.x * s, f0.y * s); u0.u.y = pkbf(f0.z * s, f0.w * s);
    u0.u.z = pkbf(f1.x * s, f1.y * s); u0.u.w = pkbf(f1.z * s, f1.w * s);
    u1.u.x = pkbf(f2.x * s, f2.y * s); u1.u.y = pkbf(f2.z * s, f2.w * s);
    u1.u.z = pkbf(f3.x * s, f3.y * s); u1.u.w = pkbf(f3.z * s, f3.w * s);
    qf0 = u0.h; qf1 = u1.h;
  }

  float rm = -INFINITY, rs = 0.f;
  f32x4 o0 = {0.f, 0.f, 0.f, 0.f}, o1 = o0, o2 = o0, o3 = o0;

  const int swzk = (a15 & 7) << 4;
  const int swzv = a15 << 3;

  for (int kb = 0; kb < N; kb += 64) {
    __syncthreads();
    {
      const int row = kb + skr;
      float4 a = {}, b = {}, c = {}, d = {};
      if (row < N) {
        const float* kp = Kb + (size_t)row * 512 + sg * 16;
        a = ((const float4*)kp)[0]; b = ((const float4*)kp)[1];
        c = ((const float4*)kp)[2]; d = ((const float4*)kp)[3];
      }
      const int sw = (skr & 7) << 4;
      u32x4 wk;
      wk.x = pkbf(a.x, a.y); wk.y = pkbf(a.z, a.w);
      wk.z = pkbf(b.x, b.y); wk.w = pkbf(b.z, b.w);
      *(u32x4*)(ktb + skr * 128 + ((sg * 32) ^ sw)) = wk;
      wk.x = pkbf(c.x, c.y); wk.y = pkbf(c.z, c.w);
      wk.z = pkbf(d.x, d.y); wk.w = pkbf(d.z, d.w);
      *(u32x4*)(ktb + skr * 128 + ((sg * 32 + 16) ^ sw)) = wk;
    }
    {
      const int r0 = kb + 4 * vsr;
      float4 f0 = {}, f1 = {}, f2 = {}, f3 = {};
      const float* vp = Vb + (size_t)r0 * 512 + 4 * vsc;
      if (r0 + 0 < N) f0 = *(const float4*)(vp);
      if (r0 + 1 < N) f1 = *(const float4*)(vp + 512);
      if (r0 + 2 < N) f2 = *(const float4*)(vp + 1024);
      if (r0 + 3 < N) f3 = *(const float4*)(vp + 1536);
      const int dd = 4 * vsc;
      const int kby = 8 * vsr;
      u32x2 wv;
      wv.x = pkbf(f0.x, f1.x); wv.y = pkbf(f2.x, f3.x);
      *(u32x2*)(vtb + (dd + 0) * 128 + (kby ^ (((dd + 0) & 15) << 3))) = wv;
      wv.x = pkbf(f0.y, f1.y); wv.y = pkbf(f2.y, f3.y);
      *(u32x2*)(vtb + (dd + 1) * 128 + (kby ^ (((dd + 1) & 15) << 3))) = wv;
      wv.x = pkbf(f0.z, f1.z); wv.y = pkbf(f2.z, f3.z);
      *(u32x2*)(vtb + (dd + 2) * 128 + (kby ^ (((dd + 2) & 15) << 3))) = wv;
      wv.x = pkbf(f0.w, f1.w); wv.y = pkbf(f2.w, f3.w);
      *(u32x2*)(vtb + (dd + 3) * 128 + (kby ^ (((dd + 3) & 15) << 3))) = wv;
    }
    __syncthreads();

    f32x4 sf0 = {0.f, 0.f, 0.f, 0.f}, sf1 = sf0, sf2 = sf0, sf3 = sf0;
#define QK(m, sfm, s2, qfr) \
    sfm = __builtin_amdgcn_mfma_f32_16x16x32_bf16( \
        *(const bf16x8*)(ktb + (16 * m + a15) * 128 + ((64 * s2 + 16 * g) ^ swzk)), \
        qfr, sfm, 0, 0, 0);
    QK(0, sf0, 0, qf0) QK(1, sf1, 0, qf0) QK(2, sf2, 0, qf0) QK(3, sf3, 0, qf0)
    QK(0, sf0, 1, qf1) QK(1, sf1, 1, qf1) QK(2, sf2, 1, qf1) QK(3, sf3, 1, qf1)
#undef QK

    if (kb + 64 > N) {
#define MSK(sfm, m) { int kk = kb + 16 * m + 4 * g; \
      if (kk + 0 >= N) sfm.x = -INFINITY; \
      if (kk + 1 >= N) sfm.y = -INFINITY; \
      if (kk + 2 >= N) sfm.z = -INFINITY; \
      if (kk + 3 >= N) sfm.w = -INFINITY; }
      MSK(sf0, 0) MSK(sf1, 1) MSK(sf2, 2) MSK(sf3, 3)
#undef MSK
    }

    float tmax = fmaxf(fmaxf(fmaxf(sf0.x, sf0.y), fmaxf(sf0.z, sf0.w)),
                       fmaxf(fmaxf(sf1.x, sf1.y), fmaxf(sf1.z, sf1.w)));
    tmax = fmaxf(tmax, fmaxf(fmaxf(fmaxf(sf2.x, sf2.y), fmaxf(sf2.z, sf2.w)),
                             fmaxf(fmaxf(sf3.x, sf3.y), fmaxf(sf3.z, sf3.w))));
    tmax = fmaxf(tmax, __shfl_xor(tmax, 16));
    tmax = fmaxf(tmax, __shfl_xor(tmax, 32));
    const float nm = fmaxf(rm, tmax);
    const float sc = __expf(rm - nm);
    float ps = 0.f;
    u32x4 pr0, pr1, pr2, pr3;
#define SMX(sfm, prm) { float e; unsigned int u; \
    e = __expf(sfm.x - nm); u = __float_as_uint(e); u += 0x7FFFu + ((u >> 16) & 1); u &= 0xFFFF0000u; ps += __uint_as_float(u); prm.x = u; \
    e = __expf(sfm.y - nm); u = __float_as_uint(e); u += 0x7FFFu + ((u >> 16) & 1); u &= 0xFFFF0000u; ps += __uint_as_float(u); prm.y = u; \
    e = __expf(sfm.z - nm); u = __float_as_uint(e); u += 0x7FFFu + ((u >> 16) & 1); u &= 0xFFFF0000u; ps += __uint_as_float(u); prm.z = u; \
    e = __expf(sfm.w - nm); u = __float_as_uint(e); u += 0x7FFFu + ((u >> 16) & 1); u &= 0xFFFF0000u; ps += __uint_as_float(u); prm.w = u; }
    SMX(sf0, pr0) SMX(sf1, pr1) SMX(sf2, pr2) SMX(sf3, pr3)
#undef SMX
    ps += __shfl_xor(ps, 16);
    ps += __shfl_xor(ps, 32);
    rs = rs * sc + ps;
    rm = nm;
    o0 *= sc; o1 *= sc; o2 *= sc; o3 *= sc;

    U8 pb0, pb1;
    pb0.u.x = (pr0.x >> 16) | pr0.y;  pb0.u.y = (pr0.z >> 16) | pr0.w;
    pb0.u.z = (pr1.x >> 16) | pr1.y;  pb0.u.w = (pr1.z >> 16) | pr1.w;
    pb1.u.x = (pr2.x >> 16) | pr2.y;  pb1.u.y = (pr2.z >> 16) | pr2.w;
    pb1.u.z = (pr3.x >> 16) | pr3.y;  pb1.u.w = (pr3.z >> 16) | pr3.w;
#define PV(md, om, s2, pbr) { \
    const char* vr = vtb + (16 * md + a15) * 128; \
    u32x2 v0 = *(const u32x2*)(vr + ((64 * s2 + 8 * g) ^ swzv)); \
    u32x2 v1 = *(const u32x2*)(vr + ((64 * s2 + 32 + 8 * g) ^ swzv)); \
    U8 av; av.u.x = v0.x; av.u.y = v0.y; av.u.z = v1.x; av.u.w = v1.y; \
    om = __builtin_amdgcn_mfma_f32_16x16x32_bf16(av.h, pbr, om, 0, 0, 0); }
    PV(0, o0, 0, pb0.h) PV(1, o1, 0, pb0.h) PV(2, o2, 0, pb0.h) PV(3, o3, 0, pb0.h)
    PV(0, o0, 1, pb1.h) PV(1, o1, 1, pb1.h) PV(2, o2, 1, pb1.h) PV(3, o3, 1, pb1.h)
#undef PV
  }

  if (q < N) {
    const float inv = 1.0f / rs;
    float* op = Ob + (size_t)q * 512 + 4 * g;
    float4 r;
    r.x = o0.x * inv; r.y = o0.y * inv; r.z = o0.z * inv; r.w = o0.w * inv;
    *(float4*)(op + 0) = r;
    r.x = o1.x * inv; r.y = o1.y * inv; r.z = o1.z * inv; r.w = o1.w * inv;
    *(float4*)(op + 16) = r;
    r.x = o2.x * inv; r.y = o2.y * inv; r.z = o2.z * inv; r.w = o2.w * inv;
    *(float4*)(op + 32) = r;
    r.x = o3.x * inv; r.y = o3.y * inv; r.z = o3.z * inv; r.w = o3.w * inv;
    *(float4*)(op + 48) = r;
  }
}

// ================= fuse =================
struct FuseB { const float* mha[2]; const float* fw[2]; const float* fb[2]; float* y[2]; int n[2]; };

__global__ __launch_bounds__(256) void fuse_b(FuseB fz) {
  int z = blockIdx.z;
  int n = fz.n[z];
  int i = blockIdx.x * 256 + threadIdx.x;
  if (i >= n * 512) return;
  size_t stride = (size_t)n * 512;
  const float* m = fz.mha[z];
  const float* fw = fz.fw[z];
  float acc = fz.fb[z][0];
  acc += fw[0] * m[i];
  acc += fw[1] * m[stride + i];
  acc += fw[2] * m[2 * stride + i];
  acc += fw[3] * m[3 * stride + i];
  fz.y[z][i] = acc;
}

// ================= launch =================
extern "C" void kernel_launch(void* const* d_in, const int* in_sizes, int n_in,
                              void* d_out, int out_size, void* d_ws, size_t ws_size,
                              hipStream_t stream) {
  const float* mirna_x = (const float*)d_in[0];
  const float* drug_x  = (const float*)d_in[1];
  const int* edge[4] = { (const int*)d_in[2], (const int*)d_in[4], (const int*)d_in[6], (const int*)d_in[8] };
  const float* attr[4] = { (const float*)d_in[3], (const float*)d_in[5], (const float*)d_in[7], (const float*)d_in[9] };
  const int m[4] = { in_sizes[2] / 2, in_sizes[4] / 2, in_sizes[6] / 2, in_sizes[8] / 2 };
  const int nn4[4] = { NM, NM, ND, ND };
  float* out = (float*)d_out;

  float* ws = (float*)d_ws;
  size_t off = 0;
  auto take = [&](size_t nelem) {
    float* r = ws + off;
    off += (nelem + 255) & ~(size_t)255;
    return r;
  };
  const size_t HN = (size_t)NM * 512, HD = (size_t)ND * 512;
  const size_t HALL = 2 * HN + 2 * HD;
  float* emb_m = take((size_t)NM * 2048);
  float* emb_d = take((size_t)ND * 2048);
  float* region = take(2 * HALL);
  float* h4[4] = { region, region + HN, region + 2 * HN, region + 2 * HN + HD };
  float* xv_m = region;
  float* xv_d = region + (size_t)NM * 2048;
  float* dis_all = take(4 * 2560);
  float* dis4[4] = { dis_all, dis_all + 2560, dis_all + 2 * 2560, dis_all + 3 * 2560 };
  int* cnt_all = (int*)take(4 * 2560);
  int* cnt4[4] = { cnt_all, cnt_all + 2560, cnt_all + 2 * 2560, cnt_all + 3 * 2560 };
  int* rp_all = (int*)take(4 * 2304);
  int* rp4[4] = { rp_all, rp_all + 2304, rp_all + 2 * 2304, rp_all + 3 * 2304 };
  int* col4[4];
  float* val4[4];
  for (int z = 0; z < 4; z++) {
    col4[z] = (int*)take(m[z]);
    val4[z] = take(m[z]);
  }
  float* Qm = take((size_t)NM * 2048);
  float* Km = take((size_t)NM * 2048);
  float* Vm = take((size_t)NM * 2048);
  float* Qd = take((size_t)ND * 2048);
  float* Kd = take((size_t)ND * 2048);
  float* Vd = take((size_t)ND * 2048);
  float* y_m = take(HN);
  float* y_d = take(HD);
  unsigned short* wt = (unsigned short*)take((size_t)16 * 131072);  // 16 x 512x512 bf16

  int pref = 0;
  int epref[5];
  for (int z = 0; z < 4; z++) { epref[z] = pref; pref += m[z]; }
  epref[4] = pref;

  // -------- weight prep: slots 0-3 W1, 4-7 W2, 8-11 mir QKVO, 12-15 drug ----
  PrepW pw;
  for (int z = 0; z < 4; z++) {
    pw.W[z] = (const float*)d_in[10 + 4 * z];
    pw.W[4 + z] = (const float*)d_in[12 + 4 * z];
    pw.W[8 + z] = (const float*)d_in[26 + z];
    pw.W[12 + z] = (const float*)d_in[32 + z];
  }
  for (int z = 0; z < 16; z++) pw.Wt[z] = wt + (size_t)z * 262144;
  prep_w<<<dim3(8, 8, 16), 256, 0, stream>>>(pw);

  // -------- CSR build --------
  hipMemsetAsync(dis_all, 0, 4 * 2560 * sizeof(float), stream);
  hipMemsetAsync(cnt_all, 0, 4 * 2560 * sizeof(int), stream);

  DegB db;
  for (int z = 0; z < 4; z++) {
    db.dst[z] = edge[z] + m[z]; db.attr[z] = attr[z];
    db.dis[z] = dis4[z]; db.cnt[z] = cnt4[z];
  }
  for (int z = 0; z < 5; z++) db.epref[z] = epref[z];
  deg_count_b<<<ceil_div(pref, 256), 256, 0, stream>>>(db);

  FinB fn;
  for (int z = 0; z < 4; z++) { fn.dis[z] = dis4[z]; fn.n[z] = nn4[z]; }
  finish_dis_b<<<dim3(ceil_div(ND, 256), 1, 4), 256, 0, stream>>>(fn);

  ScanB sb;
  for (int z = 0; z < 4; z++) { sb.cnt[z] = cnt4[z]; sb.rowptr[z] = rp4[z]; sb.n[z] = nn4[z]; }
  scan_b<<<4, 256, 0, stream>>>(sb);

  hipMemsetAsync(cnt_all, 0, 4 * 2560 * sizeof(int), stream);
  FillB fl;
  for (int z = 0; z < 4; z++) {
    fl.src[z] = edge[z]; fl.dst[z] = edge[z] + m[z]; fl.attr[z] = attr[z];
    fl.rowptr[z] = rp4[z]; fl.cur[z] = cnt4[z]; fl.col[z] = col4[z]; fl.val[z] = val4[z];
  }
  for (int z = 0; z < 5; z++) fl.epref[z] = epref[z];
  fill_b<<<ceil_div(pref, 256), 256, 0, stream>>>(fl);

  // -------- conv1 --------
  BGemm c1;
  const float* xin[4] = { mirna_x, mirna_x, drug_x, drug_x };
  for (int z = 0; z < 4; z++) {
    c1.A[z] = xin[z]; c1.Bt[z] = wt + (size_t)z * 262144; c1.C[z] = h4[z];
    c1.M[z] = nn4[z]; c1.lda[z] = 512;
  }
  for (int z = 4; z < 6; z++) { c1.A[z] = nullptr; c1.Bt[z] = nullptr; c1.C[z] = nullptr; c1.M[z] = 0; c1.lda[z] = 512; }
  gemm_mfma<<<dim3(4, ceil_div(ND, 128), 4), 256, 0, stream>>>(c1);

  float* embp[4] = { emb_m, emb_m + 1024, emb_d, emb_d + 1024 };
  GathB g1;
  for (int z = 0; z < 4; z++) {
    g1.rowptr[z] = rp4[z]; g1.col[z] = col4[z]; g1.val[z] = val4[z];
    g1.dis[z] = dis4[z]; g1.h[z] = h4[z]; g1.b[z] = (const float*)d_in[11 + 4 * z];
    g1.out[z] = embp[z]; g1.n[z] = nn4[z];
  }
  gcn_gather_b<<<dim3(ND, 1, 4), 256, 0, stream>>>(g1);

  // -------- conv2 --------
  BGemm c2 = c1;
  for (int z = 0; z < 4; z++) {
    c2.A[z] = embp[z]; c2.Bt[z] = wt + (size_t)(4 + z) * 262144; c2.C[z] = h4[z];
    c2.M[z] = nn4[z]; c2.lda[z] = 2048;
  }
  gemm_mfma<<<dim3(4, ceil_div(ND, 128), 4), 256, 0, stream>>>(c2);

  GathB g2 = g1;
  for (int z = 0; z < 4; z++) { g2.b[z] = (const float*)d_in[13 + 4 * z]; g2.out[z] = embp[z] + 512; }
  gcn_gather_b<<<dim3(ND, 1, 4), 256, 0, stream>>>(g2);

  // -------- gather to view layout --------
  GatherB gt;
  gt.emb[0] = emb_m; gt.emb[1] = emb_d; gt.xv[0] = xv_m; gt.xv[1] = xv_d;
  gt.n[0] = NM; gt.n[1] = ND;
  gather_b<<<dim3(ceil_div(ND * 2048, 256), 1, 2), 256, 0, stream>>>(gt);

  // -------- QKV projections --------
  BGemm qkv;
  float* qkvc[6] = { Qm, Km, Vm, Qd, Kd, Vd };
  for (int z = 0; z < 6; z++) {
    qkv.A[z] = (z < 3) ? xv_m : xv_d;
    qkv.Bt[z] = wt + (size_t)((z < 3) ? (8 + z) : (12 + z - 3)) * 262144;
    qkv.C[z] = qkvc[z];
    qkv.M[z] = (z < 3) ? 4 * NM : 4 * ND; qkv.lda[z] = 512;
  }
  gemm_mfma<<<dim3(4, ceil_div(4 * ND, 128), 6), 256, 0, stream>>>(qkv);

  // -------- attention (MFMA, o2 -> xv buffers) --------
  AttArgs aa;
  aa.Q[0] = Qm; aa.K[0] = Km; aa.V[0] = Vm; aa.O[0] = xv_m; aa.N[0] = NM;
  aa.Q[1] = Qd; aa.K[1] = Kd; aa.V[1] = Vd; aa.O[1] = xv_d; aa.N[1] = ND;
  attn3_kernel<<<dim3(ceil_div(ND, 64), 32, 2), 256, 0, stream>>>(aa);

  // -------- Wo --------
  BGemm wo;
  for (int z = 0; z < 2; z++) {
    wo.A[z] = (z == 0) ? xv_m : xv_d;
    wo.Bt[z] = wt + (size_t)(z == 0 ? 11 : 15) * 262144;
    wo.C[z] = (z == 0) ? Qm : Qd;
    wo.M[z] = (z == 0) ? 4 * NM : 4 * ND; wo.lda[z] = 512;
  }
  for (int z = 2; z < 6; z++) { wo.A[z] = nullptr; wo.Bt[z] = nullptr; wo.C[z] = nullptr; wo.M[z] = 0; wo.lda[z] = 512; }
  gemm_mfma<<<dim3(4, ceil_div(4 * ND, 128), 2), 256, 0, stream>>>(wo);

  // -------- fuse --------
  FuseB fz;
  fz.mha[0] = Qm; fz.mha[1] = Qd;
  fz.fw[0] = (const float*)d_in[30]; fz.fw[1] = (const float*)d_in[36];
  fz.fb[0] = (const float*)d_in[31]; fz.fb[1] = (const float*)d_in[37];
  fz.y[0] = y_m; fz.y[1] = y_d;
  fz.n[0] = NM; fz.n[1] = ND;
  fuse_b<<<dim3(ceil_div(ND * 512, 256), 1, 2), 256, 0, stream>>>(fz);

  // -------- final TN GEMM (f32) --------
  gemm_tn<<<dim3(ceil_div(ND, 64), ceil_div(NM, 64)), 256, 0, stream>>>(
      y_m, y_d, out, NM, ND, 512, NM, ND, ND);
}

// Round 8
// 829.990 us; speedup vs baseline: 12.0694x; 1.0440x over previous
//
#include <hip/hip_runtime.h>
#include <cmath>

#define NM 1043
#define ND 2166

static inline int ceil_div(int a, int b) { return (a + b - 1) / b; }

typedef __attribute__((ext_vector_type(8))) short bf16x8;
typedef __attribute__((ext_vector_type(4))) float f32x4;
typedef __attribute__((ext_vector_type(2))) unsigned int u32x2;
typedef __attribute__((ext_vector_type(4))) unsigned int u32x4;

union U8 { u32x4 u; bf16x8 h; };

__device__ inline unsigned int pkbf(float a, float b) {
  unsigned int ua = __float_as_uint(a), ub = __float_as_uint(b);
  ua += 0x7FFFu + ((ua >> 16) & 1);
  ub += 0x7FFFu + ((ub >> 16) & 1);
  return (ub & 0xFFFF0000u) | (ua >> 16);
}

__device__ inline unsigned short bf1(float a) {
  unsigned int ua = __float_as_uint(a);
  ua += 0x7FFFu + ((ua >> 16) & 1);
  return (unsigned short)(ua >> 16);
}

// ============ weight prep: W[k][n] f32 -> Wt[n][k] bf16 (16 matrices) ========
struct PrepW { const float* W[16]; unsigned short* Wt[16]; };

__global__ __launch_bounds__(256) void prep_w(PrepW p) {
  const int z = blockIdx.z;
  const float* __restrict__ W = p.W[z];
  unsigned short* __restrict__ Wt = p.Wt[z];
  const int n0 = blockIdx.x * 64, k0 = blockIdx.y * 64;
  __shared__ float Ws[64][65];
  const int tid = threadIdx.x;
#pragma unroll
  for (int it = 0; it < 16; it++) {
    int i = it * 256 + tid;
    int k = i >> 6, n = i & 63;
    Ws[k][n] = W[(size_t)(k0 + k) * 512 + n0 + n];
  }
  __syncthreads();
#pragma unroll
  for (int it = 0; it < 16; it++) {
    int i = it * 256 + tid;
    int n = i >> 6, k = i & 63;
    Wt[(size_t)(n0 + n) * 512 + k0 + k] = bf1(Ws[k][n]);
  }
}

// ============ batched MFMA GEMM: C[M,512] = A[M,512] @ W, Bt = W^T bf16 ======
struct BGemm {
  const void* A[6]; const unsigned short* Bt[6]; void* C[6];
  int M[6]; int lda[6];
};

template<int AIN_BF16, int COUT_BF16>
__global__ __launch_bounds__(256) void gemm_mfma(BGemm g) {
  const int z = blockIdx.z;
  const int M = g.M[z];
  const int bm = blockIdx.y << 7;
  if (bm >= M) return;
  const int bn = blockIdx.x << 7;
  const int lda = g.lda[z];
  const char* __restrict__ Ab = (const char*)g.A[z];
  const char* __restrict__ Btb = (const char*)g.Bt[z];

  __shared__ short As_s[128 * 64];
  __shared__ short Bs_s[128 * 64];
  char* asb = (char*)As_s;
  char* bsb = (char*)Bs_s;

  const int tid = threadIdx.x;
  const int lane = tid & 63;
  const int w = tid >> 6;
  const int wm = (w >> 1) << 6, wn = (w & 1) << 6;
  const int fr = lane & 15, kg = lane >> 4;

  f32x4 acc[4][4];
#pragma unroll
  for (int i = 0; i < 4; i++)
#pragma unroll
    for (int j = 0; j < 4; j++) acc[i][j] = (f32x4){0.f, 0.f, 0.f, 0.f};

  for (int kb = 0; kb < 512; kb += 64) {
    __syncthreads();
    // ---- stage A tile 128x64 -> bf16 LDS, swizzled ----
#pragma unroll
    for (int qi = 0; qi < 4; qi++) {
      int qid = qi * 256 + tid;
      int mm = qid >> 3, qk = qid & 7;
      u32x4 wv = {0u, 0u, 0u, 0u};
      if (bm + mm < M) {
        if (AIN_BF16) {
          wv = *(const u32x4*)(Ab + ((size_t)(bm + mm) * lda + kb + qk * 8) * 2);
        } else {
          const float* ap = (const float*)Ab + (size_t)(bm + mm) * lda + kb + qk * 8;
          float4 f0 = ((const float4*)ap)[0];
          float4 f1 = ((const float4*)ap)[1];
          wv.x = pkbf(f0.x, f0.y); wv.y = pkbf(f0.z, f0.w);
          wv.z = pkbf(f1.x, f1.y); wv.w = pkbf(f1.z, f1.w);
        }
      }
      *(u32x4*)(asb + mm * 128 + ((qk * 16) ^ ((mm & 7) << 4))) = wv;
    }
    // ---- stage Bt tile 128x64 bf16, swizzled ----
#pragma unroll
    for (int qi = 0; qi < 4; qi++) {
      int qid = qi * 256 + tid;
      int nn = qid >> 3, qk = qid & 7;
      u32x4 bv = *(const u32x4*)(Btb + (((size_t)(bn + nn)) << 10) + (kb + qk * 8) * 2);
      *(u32x4*)(bsb + nn * 128 + ((qk * 16) ^ ((nn & 7) << 4))) = bv;
    }
    __syncthreads();

#pragma unroll
    for (int ks = 0; ks < 2; ks++) {
      bf16x8 af[4], bfv[4];
#pragma unroll
      for (int i = 0; i < 4; i++) {
        int row = wm + i * 16 + fr;
        af[i] = *(const bf16x8*)(asb + row * 128 + (((ks * 64) + kg * 16) ^ ((row & 7) << 4)));
      }
#pragma unroll
      for (int j = 0; j < 4; j++) {
        int row = wn + j * 16 + fr;
        bfv[j] = *(const bf16x8*)(bsb + row * 128 + (((ks * 64) + kg * 16) ^ ((row & 7) << 4)));
      }
#pragma unroll
      for (int i = 0; i < 4; i++)
#pragma unroll
        for (int j = 0; j < 4; j++)
          acc[i][j] = __builtin_amdgcn_mfma_f32_16x16x32_bf16(af[i], bfv[j], acc[i][j], 0, 0, 0);
    }
  }

  // ---- epilogue: row = bm+wm+i*16+kg*4+r, col = bn+wn+j*16+fr ----
#pragma unroll
  for (int i = 0; i < 4; i++) {
    int m0 = bm + wm + i * 16 + kg * 4;
#pragma unroll
    for (int j = 0; j < 4; j++) {
      int n = bn + wn + j * 16 + fr;
#pragma unroll
      for (int r = 0; r < 4; r++) {
        if (m0 + r < M) {
          if (COUT_BF16) ((unsigned short*)g.C[z])[(size_t)(m0 + r) * 512 + n] = bf1(acc[i][j][r]);
          else ((float*)g.C[z])[(size_t)(m0 + r) * 512 + n] = acc[i][j][r];
        }
      }
    }
  }
}

// ================= final TN GEMM (f32, unchanged) =================
__global__ __launch_bounds__(256) void gemm_tn(
    const float* __restrict__ A, const float* __restrict__ B, float* __restrict__ C,
    int M, int N, int K, int lda, int ldb, int ldc) {
  __shared__ float As[16][65];
  __shared__ float Bs[16][65];
  const int tid = threadIdx.x;
  const int tx = tid & 15, ty = tid >> 4;
  const int bm = blockIdx.y << 6, bn = blockIdx.x << 6;
  float acc[4][4] = {};
  for (int k0 = 0; k0 < K; k0 += 16) {
    for (int i = tid; i < 16 * 64; i += 256) {
      int kk = i >> 6, mm = i & 63;
      int r = k0 + kk, c = bm + mm;
      As[kk][mm] = (r < K && c < M) ? A[(size_t)r * lda + c] : 0.f;
    }
    for (int i = tid; i < 16 * 64; i += 256) {
      int kk = i >> 6, nn = i & 63;
      int r = k0 + kk, c = bn + nn;
      Bs[kk][nn] = (r < K && c < N) ? B[(size_t)r * ldb + c] : 0.f;
    }
    __syncthreads();
#pragma unroll
    for (int kk = 0; kk < 16; kk++) {
      float a[4], b[4];
#pragma unroll
      for (int i = 0; i < 4; i++) a[i] = As[kk][ty + (i << 4)];
#pragma unroll
      for (int j = 0; j < 4; j++) b[j] = Bs[kk][tx + (j << 4)];
#pragma unroll
      for (int i = 0; i < 4; i++)
#pragma unroll
        for (int j = 0; j < 4; j++) acc[i][j] += a[i] * b[j];
    }
    __syncthreads();
  }
#pragma unroll
  for (int i = 0; i < 4; i++) {
    int r = bm + ty + (i << 4);
    if (r >= M) continue;
#pragma unroll
    for (int j = 0; j < 4; j++) {
      int c = bn + tx + (j << 4);
      if (c < N) C[(size_t)r * ldc + c] = acc[i][j];
    }
  }
}

// ================= GCN: CSR build + fused gather =================
struct DegB {
  const int* dst[4]; const float* attr[4];
  float* dis[4]; int* cnt[4];
  int epref[5];
};

__global__ __launch_bounds__(256) void deg_count_b(DegB g) {
  int et = blockIdx.x * 256 + threadIdx.x;
  if (et >= g.epref[4]) return;
  int z = (et >= g.epref[1]) + (et >= g.epref[2]) + (et >= g.epref[3]);
  int e = et - g.epref[z];
  int d = g.dst[z][e];
  atomicAdd(&g.dis[z][d], g.attr[z][e]);
  atomicAdd(&g.cnt[z][d], 1);
}

struct FinB { float* dis[4]; int n[4]; };

__global__ __launch_bounds__(256) void finish_dis_b(FinB g) {
  int z = blockIdx.z;
  int i = blockIdx.x * 256 + threadIdx.x;
  if (i < g.n[z]) g.dis[z][i] = rsqrtf(g.dis[z][i] + 1.0f);
}

struct ScanB { const int* cnt[4]; int* rowptr[4]; int n[4]; };

__global__ __launch_bounds__(256) void scan_b(ScanB s) {
  int z = blockIdx.x;
  int n = s.n[z];
  const int* cnt = s.cnt[z];
  int* rp = s.rowptr[z];
  __shared__ int sums[256];
  int tid = threadIdx.x;
  int chunk = (n + 255) >> 8;
  int start = tid * chunk;
  int local = 0;
  for (int i = 0; i < chunk; i++) {
    int idx = start + i;
    if (idx < n) local += cnt[idx];
  }
  sums[tid] = local;
  __syncthreads();
  for (int off = 1; off < 256; off <<= 1) {
    int t = (tid >= off) ? sums[tid - off] : 0;
    __syncthreads();
    sums[tid] += t;
    __syncthreads();
  }
  int base = sums[tid] - local;
  int total = sums[255];
  int run = base;
  for (int i = 0; i < chunk; i++) {
    int idx = start + i;
    if (idx < n) { rp[idx] = run; run += cnt[idx]; }
  }
  if (tid == 0) rp[n] = total;
}

struct FillB {
  const int* src[4]; const int* dst[4]; const float* attr[4];
  const int* rowptr[4]; int* cur[4]; int* col[4]; float* val[4];
  int epref[5];
};

__global__ __launch_bounds__(256) void fill_b(FillB f) {
  int et = blockIdx.x * 256 + threadIdx.x;
  if (et >= f.epref[4]) return;
  int z = (et >= f.epref[1]) + (et >= f.epref[2]) + (et >= f.epref[3]);
  int e = et - f.epref[z];
  int d = f.dst[z][e];
  int pos = f.rowptr[z][d] + atomicAdd(&f.cur[z][d], 1);
  f.col[z][pos] = f.src[z][e];
  f.val[z][pos] = f.attr[z][e];
}

struct GathB {
  const int* rowptr[4]; const int* col[4]; const float* val[4];
  const float* dis[4]; const float* h[4]; const float* b[4];
  float* out[4]; int n[4];
};

__global__ __launch_bounds__(256) void gcn_gather_b(GathB c) {
  const int z = blockIdx.z;
  const int node = blockIdx.x;
  if (node >= c.n[z]) return;
  const int tid = threadIdx.x;
  const int* __restrict__ col = c.col[z];
  const float* __restrict__ val = c.val[z];
  const float* __restrict__ dis = c.dis[z];
  const float* __restrict__ h = c.h[z];
  const int beg = c.rowptr[z][node], end = c.rowptr[z][node + 1];
  float acc0 = 0.f, acc1 = 0.f;
  int e = beg;
  for (; e + 4 <= end; e += 4) {
    int s0 = col[e], s1 = col[e + 1], s2 = col[e + 2], s3 = col[e + 3];
    float w0 = val[e] * dis[s0];
    float w1 = val[e + 1] * dis[s1];
    float w2 = val[e + 2] * dis[s2];
    float w3 = val[e + 3] * dis[s3];
    const float* p0 = h + ((size_t)s0 << 9);
    const float* p1 = h + ((size_t)s1 << 9);
    const float* p2 = h + ((size_t)s2 << 9);
    const float* p3 = h + ((size_t)s3 << 9);
    acc0 += w0 * p0[tid] + w1 * p1[tid] + w2 * p2[tid] + w3 * p3[tid];
    acc1 += w0 * p0[tid + 256] + w1 * p1[tid + 256] + w2 * p2[tid + 256] + w3 * p3[tid + 256];
  }
  for (; e < end; e++) {
    int s = col[e];
    float w = val[e] * dis[s];
    const float* p = h + ((size_t)s << 9);
    acc0 += w * p[tid];
    acc1 += w * p[tid + 256];
  }
  const float dd = dis[node];
  const float* hp = h + ((size_t)node << 9);
  float o0 = fmaxf(dd * acc0 + dd * dd * hp[tid] + c.b[z][tid], 0.f);
  float o1 = fmaxf(dd * acc1 + dd * dd * hp[tid + 256] + c.b[z][tid + 256], 0.f);
  float* op = c.out[z] + (size_t)node * 2048;
  op[tid] = o0;
  op[tid + 256] = o1;
}

// ================= view gather =================
struct GatherB { const float* emb[2]; float* xv[2]; int n[2]; };

__global__ __launch_bounds__(256) void gather_b(GatherB g) {
  int z = blockIdx.z;
  int n = g.n[z];
  size_t i = (size_t)blockIdx.x * 256 + threadIdx.x;
  if (i >= (size_t)n * 2048) return;
  int e = (int)(i & 511);
  size_t t = i >> 9;
  int v = (int)(t / n);
  int nn = (int)(t - (size_t)v * n);
  g.xv[z][i] = g.emb[z][((size_t)v * 512 + e) * n + nn];
}

// ================= attention v4: bf16 in/out, QBLK=128, 32q/wave =============
struct AttArgs {
  const unsigned short* Q[2]; const unsigned short* K[2]; const unsigned short* V[2];
  unsigned short* O[2]; int N[2];
};

__global__ __launch_bounds__(256) void attn4_kernel(AttArgs ar) {
  const int z = blockIdx.z;
  const int N = ar.N[z];
  const int qb = blockIdx.x * 128;
  if (qb >= N) return;
  const int vh = blockIdx.y, v = vh >> 3, h = vh & 7;
  const size_t base = (size_t)v * N * 512 + (size_t)h * 64;
  const unsigned short* __restrict__ Qb = ar.Q[z] + base;
  const char* __restrict__ Kc = (const char*)(ar.K[z] + base);
  const char* __restrict__ Vc = (const char*)(ar.V[z] + base);
  unsigned short* __restrict__ Ob = ar.O[z] + base;

  __shared__ short kt_s[64 * 64];
  __shared__ short vt_s[64 * 64];
  char* ktb = (char*)kt_s;
  char* vtb = (char*)vt_s;

  const int tid = threadIdx.x;
  const int lane = tid & 63;
  const int w = tid >> 6;
  const int a15 = lane & 15;
  const int g = lane >> 4;

  // Q fragments: tile A rows qb+w*32+a15, tile B +16; bf16 direct loads
  const int qA = qb + w * 32 + a15;
  const int qB = qA + 16;
  bf16x8 qfA0 = {}, qfA1 = {}, qfB0 = {}, qfB1 = {};
  if (qA < N) {
    qfA0 = *(const bf16x8*)(Qb + (size_t)qA * 512 + g * 8);
    qfA1 = *(const bf16x8*)(Qb + (size_t)qA * 512 + 32 + g * 8);
  }
  if (qB < N) {
    qfB0 = *(const bf16x8*)(Qb + (size_t)qB * 512 + g * 8);
    qfB1 = *(const bf16x8*)(Qb + (size_t)qB * 512 + 32 + g * 8);
  }

  float rmA = -INFINITY, rsA = 0.f, rmB = -INFINITY, rsB = 0.f;
  f32x4 oA0 = {0.f, 0.f, 0.f, 0.f}, oA1 = oA0, oA2 = oA0, oA3 = oA0;
  f32x4 oB0 = oA0, oB1 = oA0, oB2 = oA0, oB3 = oA0;

  const int swzk = (a15 & 7) << 4;
  const int swzv = a15 << 3;
  const int skr = tid >> 2, skq = (tid & 3) * 16;  // K staging
  const int vsr = tid & 15, vsc = tid >> 4;        // V staging

  for (int kb = 0; kb < N; kb += 64) {
    __syncthreads();
    // ---- stage K (bf16 copy, swizzled) ----
    {
      const int sw = (skr & 7) << 4;
      const char* kp = Kc + (size_t)(kb + skr) * 1024;
      u32x4 k0 = {0u,0u,0u,0u}, k1 = {0u,0u,0u,0u};
      if (kb + skr < N) {
        k0 = *(const u32x4*)(kp + skq);
        k1 = *(const u32x4*)(kp + skq + 64);
      }
      *(u32x4*)(ktb + skr * 128 + (skq ^ sw)) = k0;
      *(u32x4*)(ktb + skr * 128 + ((skq + 64) ^ sw)) = k1;
    }
    // ---- stage V transposed (register 4x4 bf16 transpose, swizzled) ----
    {
      const int r0 = kb + 4 * vsr;
      u32x2 i0 = {0u,0u}, i1 = {0u,0u}, i2 = {0u,0u}, i3 = {0u,0u};
      const char* vp = Vc + (size_t)r0 * 1024 + vsc * 8;
      if (r0 + 0 < N) i0 = *(const u32x2*)(vp);
      if (r0 + 1 < N) i1 = *(const u32x2*)(vp + 1024);
      if (r0 + 2 < N) i2 = *(const u32x2*)(vp + 2048);
      if (r0 + 3 < N) i3 = *(const u32x2*)(vp + 3072);
      const int dd = 4 * vsc, kby = 8 * vsr;
      u32x2 o;
      o.x = (i0.x & 0xFFFFu) | (i1.x << 16); o.y = (i2.x & 0xFFFFu) | (i3.x << 16);
      *(u32x2*)(vtb + (dd + 0) * 128 + (kby ^ (((dd + 0) & 15) << 3))) = o;
      o.x = (i0.x >> 16) | (i1.x & 0xFFFF0000u); o.y = (i2.x >> 16) | (i3.x & 0xFFFF0000u);
      *(u32x2*)(vtb + (dd + 1) * 128 + (kby ^ (((dd + 1) & 15) << 3))) = o;
      o.x = (i0.y & 0xFFFFu) | (i1.y << 16); o.y = (i2.y & 0xFFFFu) | (i3.y << 16);
      *(u32x2*)(vtb + (dd + 2) * 128 + (kby ^ (((dd + 2) & 15) << 3))) = o;
      o.x = (i0.y >> 16) | (i1.y & 0xFFFF0000u); o.y = (i2.y >> 16) | (i3.y & 0xFFFF0000u);
      *(u32x2*)(vtb + (dd + 3) * 128 + (kby ^ (((dd + 3) & 15) << 3))) = o;
    }
    __syncthreads();

    // ---- QK^T for both q-tiles (K fragments shared) ----
    f32x4 sA0 = {0.f,0.f,0.f,0.f}, sA1 = sA0, sA2 = sA0, sA3 = sA0;
    f32x4 sB0 = sA0, sB1 = sA0, sB2 = sA0, sB3 = sA0;
#define QK2(m, sAm, sBm, s2, qfa, qfb) { \
    bf16x8 kf = *(const bf16x8*)(ktb + (16 * m + a15) * 128 + ((64 * s2 + 16 * g) ^ swzk)); \
    sAm = __builtin_amdgcn_mfma_f32_16x16x32_bf16(kf, qfa, sAm, 0, 0, 0); \
    sBm = __builtin_amdgcn_mfma_f32_16x16x32_bf16(kf, qfb, sBm, 0, 0, 0); }
    QK2(0, sA0, sB0, 0, qfA0, qfB0) QK2(1, sA1, sB1, 0, qfA0, qfB0)
    QK2(2, sA2, sB2, 0, qfA0, qfB0) QK2(3, sA3, sB3, 0, qfA0, qfB0)
    QK2(0, sA0, sB0, 1, qfA1, qfB1) QK2(1, sA1, sB1, 1, qfA1, qfB1)
    QK2(2, sA2, sB2, 1, qfA1, qfB1) QK2(3, sA3, sB3, 1, qfA1, qfB1)
#undef QK2

    // scale 1/sqrt(64)
    sA0 *= 0.125f; sA1 *= 0.125f; sA2 *= 0.125f; sA3 *= 0.125f;
    sB0 *= 0.125f; sB1 *= 0.125f; sB2 *= 0.125f; sB3 *= 0.125f;

    // ---- mask tail keys ----
    if (kb + 64 > N) {
#define MSK(sfm, sgm, m) { int kk = kb + 16 * m + 4 * g; \
      if (kk + 0 >= N) { sfm.x = -INFINITY; sgm.x = -INFINITY; } \
      if (kk + 1 >= N) { sfm.y = -INFINITY; sgm.y = -INFINITY; } \
      if (kk + 2 >= N) { sfm.z = -INFINITY; sgm.z = -INFINITY; } \
      if (kk + 3 >= N) { sfm.w = -INFINITY; sgm.w = -INFINITY; } }
      MSK(sA0, sB0, 0) MSK(sA1, sB1, 1) MSK(sA2, sB2, 2) MSK(sA3, sB3, 3)
#undef MSK
    }

    // ---- online softmax + PV per q-tile ----
#define SOFTMAX_PV(sf0, sf1, sf2, sf3, rm, rs, q0, q1, q2, q3) { \
    float tmax = fmaxf(fmaxf(fmaxf(sf0.x, sf0.y), fmaxf(sf0.z, sf0.w)), \
                       fmaxf(fmaxf(sf1.x, sf1.y), fmaxf(sf1.z, sf1.w))); \
    tmax = fmaxf(tmax, fmaxf(fmaxf(fmaxf(sf2.x, sf2.y), fmaxf(sf2.z, sf2.w)), \
                             fmaxf(fmaxf(sf3.x, sf3.y), fmaxf(sf3.z, sf3.w)))); \
    tmax = fmaxf(tmax, __shfl_xor(tmax, 16)); \
    tmax = fmaxf(tmax, __shfl_xor(tmax, 32)); \
    const float nm = fmaxf(rm, tmax); \
    const float sc = __expf(rm - nm); \
    float ps = 0.f; \
    u32x4 pr0, pr1, pr2, pr3; \
    SMX(sf0, pr0) SMX(sf1, pr1) SMX(sf2, pr2) SMX(sf3, pr3) \
    ps += __shfl_xor(ps, 16); \
    ps += __shfl_xor(ps, 32); \
    rs = rs * sc + ps; \
    rm = nm; \
    q0 *= sc; q1 *= sc; q2 *= sc; q3 *= sc; \
    U8 pb0, pb1; \
    pb0.u.x = (pr0.x >> 16) | pr0.y;  pb0.u.y = (pr0.z >> 16) | pr0.w; \
    pb0.u.z = (pr1.x >> 16) | pr1.y;  pb0.u.w = (pr1.z >> 16) | pr1.w; \
    pb1.u.x = (pr2.x >> 16) | pr2.y;  pb1.u.y = (pr2.z >> 16) | pr2.w; \
    pb1.u.z = (pr3.x >> 16) | pr3.y;  pb1.u.w = (pr3.z >> 16) | pr3.w; \
    PV(0, q0, 0, pb0.h) PV(1, q1, 0, pb0.h) PV(2, q2, 0, pb0.h) PV(3, q3, 0, pb0.h) \
    PV(0, q0, 1, pb1.h) PV(1, q1, 1, pb1.h) PV(2, q2, 1, pb1.h) PV(3, q3, 1, pb1.h) }

#define SMX(sfm, prm) { float e; unsigned int u; \
    e = __expf(sfm.x - nm); u = __float_as_uint(e); u += 0x7FFFu + ((u >> 16) & 1); u &= 0xFFFF0000u; ps += __uint_as_float(u); prm.x = u; \
    e = __expf(sfm.y - nm); u = __float_as_uint(e); u += 0x7FFFu + ((u >> 16) & 1); u &= 0xFFFF0000u; ps += __uint_as_float(u); prm.y = u; \
    e = __expf(sfm.z - nm); u = __float_as_uint(e); u += 0x7FFFu + ((u >> 16) & 1); u &= 0xFFFF0000u; ps += __uint_as_float(u); prm.z = u; \
    e = __expf(sfm.w - nm); u = __float_as_uint(e); u += 0x7FFFu + ((u >> 16) & 1); u &= 0xFFFF0000u; ps += __uint_as_float(u); prm.w = u; }
#define PV(md, om, s2, pbr) { \
    const char* vr = vtb + (16 * md + a15) * 128; \
    u32x2 v0 = *(const u32x2*)(vr + ((64 * s2 + 8 * g) ^ swzv)); \
    u32x2 v1 = *(const u32x2*)(vr + ((64 * s2 + 32 + 8 * g) ^ swzv)); \
    U8 av; av.u.x = v0.x; av.u.y = v0.y; av.u.z = v1.x; av.u.w = v1.y; \
    om = __builtin_amdgcn_mfma_f32_16x16x32_bf16(av.h, pbr, om, 0, 0, 0); }

    SOFTMAX_PV(sA0, sA1, sA2, sA3, rmA, rsA, oA0, oA1, oA2, oA3)
    SOFTMAX_PV(sB0, sB1, sB2, sB3, rmB, rsB, oB0, oB1, oB2, oB3)
#undef PV
#undef SMX
#undef SOFTMAX_PV
  }

  // ---- store O bf16 (row q, d = 16*md + 4g + r) ----
  if (qA < N) {
    const float inv = 1.0f / rsA;
    char* op = (char*)(Ob + (size_t)qA * 512) + g * 8;
    u32x2 r;
    r.x = pkbf(oA0.x * inv, oA0.y * inv); r.y = pkbf(oA0.z * inv, oA0.w * inv);
    *(u32x2*)(op) = r;
    r.x = pkbf(oA1.x * inv, oA1.y * inv); r.y = pkbf(oA1.z * inv, oA1.w * inv);
    *(u32x2*)(op + 32) = r;
    r.x = pkbf(oA2.x * inv, oA2.y * inv); r.y = pkbf(oA2.z * inv, oA2.w * inv);
    *(u32x2*)(op + 64) = r;
    r.x = pkbf(oA3.x * inv, oA3.y * inv); r.y = pkbf(oA3.z * inv, oA3.w * inv);
    *(u32x2*)(op + 96) = r;
  }
  if (qB < N) {
    const float inv = 1.0f / rsB;
    char* op = (char*)(Ob + (size_t)qB * 512) + g * 8;
    u32x2 r;
    r.x = pkbf(oB0.x * inv, oB0.y * inv); r.y = pkbf(oB0.z * inv, oB0.w * inv);
    *(u32x2*)(op) = r;
    r.x = pkbf(oB1.x * inv, oB1.y * inv); r.y = pkbf(oB1.z * inv, oB1.w * inv);
    *(u32x2*)(op + 32) = r;
    r.x = pkbf(oB2.x * inv, oB2.y * inv); r.y = pkbf(oB2.z * inv, oB2.w * inv);
    *(u32x2*)(op + 64) = r;
    r.x = pkbf(oB3.x * inv, oB3.y * inv); r.y = pkbf(oB3.z * inv, oB3.w * inv);
    *(u32x2*)(op + 96) = r;
  }
}

// ================= fuse =================
struct FuseB { const float* mha[2]; const float* fw[2]; const float* fb[2]; float* y[2]; int n[2]; };

__global__ __launch_bounds__(256) void fuse_b(FuseB fz) {
  int z = blockIdx.z;
  int n = fz.n[z];
  int i = blockIdx.x * 256 + threadIdx.x;
  if (i >= n * 512) return;
  size_t stride = (size_t)n * 512;
  const float* m = fz.mha[z];
  const float* fw = fz.fw[z];
  float acc = fz.fb[z][0];
  acc += fw[0] * m[i];
  acc += fw[1] * m[stride + i];
  acc += fw[2] * m[2 * stride + i];
  acc += fw[3] * m[3 * stride + i];
  fz.y[z][i] = acc;
}

// ================= launch =================
extern "C" void kernel_launch(void* const* d_in, const int* in_sizes, int n_in,
                              void* d_out, int out_size, void* d_ws, size_t ws_size,
                              hipStream_t stream) {
  const float* mirna_x = (const float*)d_in[0];
  const float* drug_x  = (const float*)d_in[1];
  const int* edge[4] = { (const int*)d_in[2], (const int*)d_in[4], (const int*)d_in[6], (const int*)d_in[8] };
  const float* attr[4] = { (const float*)d_in[3], (const float*)d_in[5], (const float*)d_in[7], (const float*)d_in[9] };
  const int m[4] = { in_sizes[2] / 2, in_sizes[4] / 2, in_sizes[6] / 2, in_sizes[8] / 2 };
  const int nn4[4] = { NM, NM, ND, ND };
  float* out = (float*)d_out;

  float* ws = (float*)d_ws;
  size_t off = 0;
  auto take = [&](size_t nelem) {
    float* r = ws + off;
    off += (nelem + 255) & ~(size_t)255;
    return r;
  };
  const size_t HN = (size_t)NM * 512, HD = (size_t)ND * 512;
  const size_t HALL = 2 * HN + 2 * HD;
  float* emb_m = take((size_t)NM * 2048);
  float* emb_d = take((size_t)ND * 2048);
  float* region = take(2 * HALL);
  float* h4[4] = { region, region + HN, region + 2 * HN, region + 2 * HN + HD };
  float* xv_m = region;
  float* xv_d = region + (size_t)NM * 2048;
  float* dis_all = take(4 * 2560);
  float* dis4[4] = { dis_all, dis_all + 2560, dis_all + 2 * 2560, dis_all + 3 * 2560 };
  int* cnt_all = (int*)take(4 * 2560);
  int* cnt4[4] = { cnt_all, cnt_all + 2560, cnt_all + 2 * 2560, cnt_all + 3 * 2560 };
  int* rp_all = (int*)take(4 * 2304);
  int* rp4[4] = { rp_all, rp_all + 2304, rp_all + 2 * 2304, rp_all + 3 * 2304 };
  int* col4[4];
  float* val4[4];
  for (int z = 0; z < 4; z++) {
    col4[z] = (int*)take(m[z]);
    val4[z] = take(m[z]);
  }
  unsigned short* Qm = (unsigned short*)take((size_t)NM * 2048);
  unsigned short* Km = (unsigned short*)take((size_t)NM * 2048);
  unsigned short* Vm = (unsigned short*)take((size_t)NM * 2048);
  unsigned short* Qd = (unsigned short*)take((size_t)ND * 2048);
  unsigned short* Kd = (unsigned short*)take((size_t)ND * 2048);
  unsigned short* Vd = (unsigned short*)take((size_t)ND * 2048);
  float* mha_m = take((size_t)NM * 2048);
  float* mha_d = take((size_t)ND * 2048);
  float* y_m = take(HN);
  float* y_d = take(HD);
  unsigned short* wt = (unsigned short*)take((size_t)16 * 131072);

  int pref = 0;
  int epref[5];
  for (int z = 0; z < 4; z++) { epref[z] = pref; pref += m[z]; }
  epref[4] = pref;

  // -------- weight prep: 0-3 W1, 4-7 W2, 8-11 mir QKVO, 12-15 drug --------
  PrepW pw;
  for (int z = 0; z < 4; z++) {
    pw.W[z] = (const float*)d_in[10 + 4 * z];
    pw.W[4 + z] = (const float*)d_in[12 + 4 * z];
    pw.W[8 + z] = (const float*)d_in[26 + z];
    pw.W[12 + z] = (const float*)d_in[32 + z];
  }
  for (int z = 0; z < 16; z++) pw.Wt[z] = wt + (size_t)z * 262144;
  prep_w<<<dim3(8, 8, 16), 256, 0, stream>>>(pw);

  // -------- CSR build --------
  hipMemsetAsync(dis_all, 0, 4 * 2560 * sizeof(float), stream);
  hipMemsetAsync(cnt_all, 0, 4 * 2560 * sizeof(int), stream);

  DegB db;
  for (int z = 0; z < 4; z++) {
    db.dst[z] = edge[z] + m[z]; db.attr[z] = attr[z];
    db.dis[z] = dis4[z]; db.cnt[z] = cnt4[z];
  }
  for (int z = 0; z < 5; z++) db.epref[z] = epref[z];
  deg_count_b<<<ceil_div(pref, 256), 256, 0, stream>>>(db);

  FinB fn;
  for (int z = 0; z < 4; z++) { fn.dis[z] = dis4[z]; fn.n[z] = nn4[z]; }
  finish_dis_b<<<dim3(ceil_div(ND, 256), 1, 4), 256, 0, stream>>>(fn);

  ScanB sb;
  for (int z = 0; z < 4; z++) { sb.cnt[z] = cnt4[z]; sb.rowptr[z] = rp4[z]; sb.n[z] = nn4[z]; }
  scan_b<<<4, 256, 0, stream>>>(sb);

  hipMemsetAsync(cnt_all, 0, 4 * 2560 * sizeof(int), stream);
  FillB fl;
  for (int z = 0; z < 4; z++) {
    fl.src[z] = edge[z]; fl.dst[z] = edge[z] + m[z]; fl.attr[z] = attr[z];
    fl.rowptr[z] = rp4[z]; fl.cur[z] = cnt4[z]; fl.col[z] = col4[z]; fl.val[z] = val4[z];
  }
  for (int z = 0; z < 5; z++) fl.epref[z] = epref[z];
  fill_b<<<ceil_div(pref, 256), 256, 0, stream>>>(fl);

  // -------- conv1 --------
  BGemm c1;
  const float* xin[4] = { mirna_x, mirna_x, drug_x, drug_x };
  for (int z = 0; z < 4; z++) {
    c1.A[z] = xin[z]; c1.Bt[z] = wt + (size_t)z * 262144; c1.C[z] = h4[z];
    c1.M[z] = nn4[z]; c1.lda[z] = 512;
  }
  for (int z = 4; z < 6; z++) { c1.A[z] = nullptr; c1.Bt[z] = nullptr; c1.C[z] = nullptr; c1.M[z] = 0; c1.lda[z] = 512; }
  gemm_mfma<0, 0><<<dim3(4, ceil_div(ND, 128), 4), 256, 0, stream>>>(c1);

  float* embp[4] = { emb_m, emb_m + 1024, emb_d, emb_d + 1024 };
  GathB g1;
  for (int z = 0; z < 4; z++) {
    g1.rowptr[z] = rp4[z]; g1.col[z] = col4[z]; g1.val[z] = val4[z];
    g1.dis[z] = dis4[z]; g1.h[z] = h4[z]; g1.b[z] = (const float*)d_in[11 + 4 * z];
    g1.out[z] = embp[z]; g1.n[z] = nn4[z];
  }
  gcn_gather_b<<<dim3(ND, 1, 4), 256, 0, stream>>>(g1);

  // -------- conv2 --------
  BGemm c2 = c1;
  for (int z = 0; z < 4; z++) {
    c2.A[z] = embp[z]; c2.Bt[z] = wt + (size_t)(4 + z) * 262144; c2.C[z] = h4[z];
    c2.M[z] = nn4[z]; c2.lda[z] = 2048;
  }
  gemm_mfma<0, 0><<<dim3(4, ceil_div(ND, 128), 4), 256, 0, stream>>>(c2);

  GathB g2 = g1;
  for (int z = 0; z < 4; z++) { g2.b[z] = (const float*)d_in[13 + 4 * z]; g2.out[z] = embp[z] + 512; }
  gcn_gather_b<<<dim3(ND, 1, 4), 256, 0, stream>>>(g2);

  // -------- gather to view layout --------
  GatherB gt;
  gt.emb[0] = emb_m; gt.emb[1] = emb_d; gt.xv[0] = xv_m; gt.xv[1] = xv_d;
  gt.n[0] = NM; gt.n[1] = ND;
  gather_b<<<dim3(ceil_div(ND * 2048, 256), 1, 2), 256, 0, stream>>>(gt);

  // -------- QKV projections (bf16 out) --------
  BGemm qkv;
  unsigned short* qkvc[6] = { Qm, Km, Vm, Qd, Kd, Vd };
  for (int z = 0; z < 6; z++) {
    qkv.A[z] = (z < 3) ? xv_m : xv_d;
    qkv.Bt[z] = wt + (size_t)((z < 3) ? (8 + z) : (12 + z - 3)) * 262144;
    qkv.C[z] = qkvc[z];
    qkv.M[z] = (z < 3) ? 4 * NM : 4 * ND; qkv.lda[z] = 512;
  }
  gemm_mfma<0, 1><<<dim3(4, ceil_div(4 * ND, 128), 6), 256, 0, stream>>>(qkv);

  // -------- attention (bf16 in/out, O -> xv buffers as bf16) --------
  AttArgs aa;
  aa.Q[0] = Qm; aa.K[0] = Km; aa.V[0] = Vm; aa.O[0] = (unsigned short*)xv_m; aa.N[0] = NM;
  aa.Q[1] = Qd; aa.K[1] = Kd; aa.V[1] = Vd; aa.O[1] = (unsigned short*)xv_d; aa.N[1] = ND;
  attn4_kernel<<<dim3(ceil_div(ND, 128), 32, 2), 256, 0, stream>>>(aa);

  // -------- Wo (bf16 A in) --------
  BGemm wo;
  for (int z = 0; z < 2; z++) {
    wo.A[z] = (z == 0) ? xv_m : xv_d;
    wo.Bt[z] = wt + (size_t)(z == 0 ? 11 : 15) * 262144;
    wo.C[z] = (z == 0) ? mha_m : mha_d;
    wo.M[z] = (z == 0) ? 4 * NM : 4 * ND; wo.lda[z] = 512;
  }
  for (int z = 2; z < 6; z++) { wo.A[z] = nullptr; wo.Bt[z] = nullptr; wo.C[z] = nullptr; wo.M[z] = 0; wo.lda[z] = 512; }
  gemm_mfma<1, 0><<<dim3(4, ceil_div(4 * ND, 128), 2), 256, 0, stream>>>(wo);

  // -------- fuse --------
  FuseB fz;
  fz.mha[0] = mha_m; fz.mha[1] = mha_d;
  fz.fw[0] = (const float*)d_in[30]; fz.fw[1] = (const float*)d_in[36];
  fz.fb[0] = (const float*)d_in[31]; fz.fb[1] = (const float*)d_in[37];
  fz.y[0] = y_m; fz.y[1] = y_d;
  fz.n[0] = NM; fz.n[1] = ND;
  fuse_b<<<dim3(ceil_div(ND * 512, 256), 1, 2), 256, 0, stream>>>(fz);

  // -------- final TN GEMM (f32) --------
  gemm_tn<<<dim3(ceil_div(ND, 64), ceil_div(NM, 64)), 256, 0, stream>>>(
      y_m, y_d, out, NM, ND, 512, NM, ND, ND);
}